// Round 1
// baseline (1226.921 us; speedup 1.0000x reference)
//
#include <hip/hip_runtime.h>
#include <stdint.h>

typedef __bf16 bf16_t;
typedef __bf16 bf16x8 __attribute__((ext_vector_type(8)));
typedef float f32x4 __attribute__((ext_vector_type(4)));

#define DEVINL __device__ __forceinline__

DEVINL float bf2f(bf16_t h){ return (float)h; }
DEVINL bf16_t f2bf(float f){ return (bf16_t)f; }

// async 16B global -> LDS (wave-uniform LDS base + lane*16)
DEVINL void g2l16(const void* g, void* l){
  __builtin_amdgcn_global_load_lds(
      (const __attribute__((address_space(1))) uint32_t*)g,
      (__attribute__((address_space(3))) uint32_t*)l, 16, 0, 0);
}

// ---------------- workspace layout (bytes) ----------------
// A64 : [16][66][66][256] bf16  (64x64 + halo)       35,684,352
// SB0..SB3 : [16][34][34][256] bf16 (32x32 + halo)    9,469,952 each
// stats: 11 slots x 512 f32                              22,528
// cbn  : 512 f32
// Wp   : repacked bf16 weights (4,849,664 elems)
// scores: [16384][512] f32
#define A64_BYTES   35684352
#define SB_BYTES    9469952
#define SB0_OFF     35684352
#define STATS_OFF   73564160
#define ZERO_BYTES  73586688          // A64 + 4*SB + stats
#define CBN_OFF     73586688
#define WP_OFF      73588736
#define SCORES_OFF  83288064
#define WS_NEEDED   116842496
// Wp element offsets
#define WP_RB3(i) (1048576 + (i)*655360)
#define WP_RB1(i) (1048576 + (i)*655360 + 589824)
#define WP_CT     3670016
#define WP_CB     4718592

// ---------------- zero ----------------
__global__ __launch_bounds__(256) void k_zero(uint4* __restrict__ p, int n16){
  int i = blockIdx.x*256 + threadIdx.x;
  if (i < n16) p[i] = make_uint4(0,0,0,0);
}

// ---------------- weight repack (all layers + codebook) ----------------
__global__ __launch_bounds__(256) void k_repack(
    const float* __restrict__ ec2_w, const float* __restrict__ rb_c3_w,
    const float* __restrict__ rb_c1_w, const float* __restrict__ dct1_w,
    const float* __restrict__ codebook, bf16_t* __restrict__ wp)
{
  int idx = blockIdx.x*256 + threadIdx.x;
  if (idx >= 4849664) return;
  int l = idx; float v;
  if (l < 1048576) {                       // ec2: [t16][co][ci] <- [co][ci][ky][kx]
    int t = l>>16, co = (l>>8)&255, ci = l&255;
    v = ec2_w[co*4096 + ci*16 + t];
  } else {
    l -= 1048576;
    if (l < 2621440) {                     // resblocks
      int i = l / 655360;
      int r = l - i*655360;
      if (r < 589824) {                    // c3: [t9][co][ci]
        int t = r>>16, co = (r>>8)&255, ci = r&255;
        v = rb_c3_w[i*589824 + co*2304 + ci*9 + t];
      } else {                             // c1: [co][ci]
        r -= 589824;
        int co = r>>8, ci = r&255;
        v = rb_c1_w[i*65536 + co*256 + ci];
      }
    } else {
      l -= 2621440;
      if (l < 1048576) {                   // convT1: [par4][t4][co][ci] <- w[ci][co][ky][kx]
        int z = l>>18, r = l&262143, t = r>>16, co = (r>>8)&255, ci = r&255;
        int py = z>>1, px = z&1, a = t>>1, b = t&1;
        int ky = 2*a + 1 - py, kx = 2*b + 1 - px;
        v = dct1_w[ci*4096 + co*16 + ky*4 + kx];
      } else {                             // codebook [k][d]
        l -= 1048576;
        v = codebook[l];
      }
    }
  }
  wp[idx] = f2bf(v);
}

// ---------------- codebook norms ----------------
__global__ __launch_bounds__(256) void k_cbnorm(const float* __restrict__ cb, float* __restrict__ out){
  int k = blockIdx.x*256 + threadIdx.x;   // < 512
  float s = 0.f;
  for (int d = 0; d < 256; d++){ float v = cb[k*256 + d]; s += v*v; }
  out[k] = s;
}

// ---------------- encoder conv1: 3->256 k4 s2 p1, x fp32 NCHW -> A64 bf16 NHWC halo ----------------
__global__ __launch_bounds__(256) void k_convin(const float* __restrict__ x, const float* __restrict__ w,
    const float* __restrict__ bias, bf16_t* __restrict__ out)
{
  int co = threadIdx.x;
  float wr[48];
#pragma unroll
  for (int j = 0; j < 12; j++){
    float4 f = *(const float4*)(w + co*48 + j*4);
    wr[j*4+0]=f.x; wr[j*4+1]=f.y; wr[j*4+2]=f.z; wr[j*4+3]=f.w;
  }
  float bco = bias[co];
  int p0 = blockIdx.x * 16;
  for (int pi = 0; pi < 16; pi++){
    int p = p0 + pi;
    int nn = p >> 12, sp = p & 4095, oy = sp >> 6, ox = sp & 63;
    float acc = bco;
#pragma unroll
    for (int ky = 0; ky < 4; ky++){
      int iy = 2*oy + ky - 1;
      if (iy < 0 || iy > 127) continue;
#pragma unroll
      for (int kx = 0; kx < 4; kx++){
        int ix = 2*ox + kx - 1;
        if (ix < 0 || ix > 127) continue;
#pragma unroll
        for (int ci = 0; ci < 3; ci++)
          acc += x[((size_t)((nn*3+ci)*128 + iy))*128 + ix] * wr[ci*16 + ky*4 + kx];
      }
    }
    out[((size_t)((nn*66 + oy+1)*66 + ox+1))*256 + co] = f2bf(acc);
  }
}

// ---------------- BN stats: per-channel sum/sumsq over interior ----------------
__global__ __launch_bounds__(256) void k_bnstats(const bf16_t* __restrict__ buf, float* __restrict__ stat, int hwlog)
{
  int HW = 1 << hwlog, IW = HW + 2;
  int P = 16 << (2*hwlog);
  int c = threadIdx.x;
  float s = 0.f, s2 = 0.f;
  for (int p = blockIdx.x; p < P; p += gridDim.x){
    int xx = p & (HW-1), yy = (p >> hwlog) & (HW-1), nn = p >> (2*hwlog);
    float v = bf2f(buf[((size_t)((nn*IW + yy+1)*IW + xx+1))*256 + c]);
    s += v; s2 += v*v;
  }
  atomicAdd(&stat[c], s);
  atomicAdd(&stat[256 + c], s2);
}

// ---------------- BN apply + ReLU (interior only; halo stays 0) ----------------
__global__ __launch_bounds__(256) void k_bnapply(const bf16_t* __restrict__ in, bf16_t* __restrict__ out,
    const float* __restrict__ stat, const float* __restrict__ g, const float* __restrict__ b,
    int hwlog, float invc)
{
  int idx = blockIdx.x*256 + threadIdx.x;
  int HW = 1 << hwlog, IW = HW + 2;
  int c = idx & 255, p = idx >> 8;
  int xx = p & (HW-1), yy = (p >> hwlog) & (HW-1), nn = p >> (2*hwlog);
  float mean = stat[c]*invc;
  float var  = stat[256+c]*invc - mean*mean;
  float sc = g[c] * rsqrtf(var + 1e-5f);
  float sh = b[c] - mean*sc;
  size_t a = ((size_t)((nn*IW + yy+1)*IW + xx+1))*256 + c;
  float v = bf2f(in[a])*sc + sh;
  out[a] = f2bf(fmaxf(v, 0.f));
}

// ---------------- implicit-GEMM conv (MFMA bf16), M=16384, 128x128 tile, BK=32 ----------------
// MODE: 0=k4s2 (in 66-halo), 1=k3s1 (34), 2=k1 (34), 3=convT k4s2 parity (in 34, out 66)
template<int MODE>
__global__ __launch_bounds__(256) void k_gemm(
    const bf16_t* __restrict__ in, const bf16_t* __restrict__ wp,
    const float* __restrict__ bias, const bf16_t* __restrict__ res,
    bf16_t* __restrict__ outb, float* __restrict__ outf,
    int out_mode, float alpha)
{
  constexpr int TAPS = (MODE==0)?16:(MODE==1)?9:(MODE==2)?1:4;
  constexpr int IW   = (MODE==0)?66:34;
  const int N = gridDim.y * 128;

  __shared__ __align__(16) bf16_t As[128*32];
  __shared__ __align__(16) bf16_t Bs[128*32];

  const int tid  = threadIdx.x;
  const int lane = tid & 63;
  const int wave = tid >> 6;
  const int m0   = blockIdx.x * 128;
  const int n0   = blockIdx.y * 128;
  int py = 0, px = 0;
  const bf16_t* wpp = wp;
  if (MODE == 3){ py = blockIdx.z >> 1; px = blockIdx.z & 1; wpp += (size_t)blockIdx.z * 262144; }

  // staging slot precompute: slot = wave*128 + j*64 + lane; m = slot>>2, k16 = slot&3
  int abase[2];  // pbase*256 + k8 (elems); tap adds toff*256 + ci0
  int bbase[2];
#pragma unroll
  for (int j = 0; j < 2; j++){
    int s = wave*128 + j*64 + lane;
    int ml = s >> 2, k8 = (s & 3) * 8;
    int m = m0 + ml;
    int nn = m >> 10, sp = m & 1023, oy = sp >> 5, ox = sp & 31;
    int pbase;
    if (MODE == 0)      pbase = (nn*66 + 2*oy)*66 + 2*ox;
    else if (MODE == 3) pbase = (nn*34 + oy + 1 + py)*34 + ox + 1 + px;
    else                pbase = (nn*34 + oy)*34 + ox;
    abase[j] = pbase*256 + k8;
    bbase[j] = (n0 + ml)*256 + k8;
  }

  f32x4 acc[4][4];
#pragma unroll
  for (int i = 0; i < 4; i++)
#pragma unroll
    for (int j = 0; j < 4; j++) acc[i][j] = (f32x4){0.f,0.f,0.f,0.f};

  const int wm = wave >> 1, wn = wave & 1;
  const int mf = lane & 15;
  const int kq = lane >> 4;

  for (int chunk = 0; chunk < TAPS*8; ++chunk){
    int t   = chunk >> 3;
    int ci0 = (chunk & 7) * 32;
    int toff;
    if (MODE == 0)      toff = (t >> 2)*66 + (t & 3);
    else if (MODE == 1){ int ky = t/3; toff = ky*34 + (t - ky*3); }
    else if (MODE == 2) toff = 35;                    // (+1)*34 + 1
    else                toff = -((t >> 1)*34 + (t & 1));
#pragma unroll
    for (int j = 0; j < 2; j++)
      g2l16(in + abase[j] + toff*256 + ci0, As + (wave*128 + j*64)*8);
#pragma unroll
    for (int j = 0; j < 2; j++)
      g2l16(wpp + (size_t)t*N*256 + bbase[j] + ci0, Bs + (wave*128 + j*64)*8);
    __syncthreads();

    bf16x8 af[4], bfr[4];
#pragma unroll
    for (int i = 0; i < 4; i++)
      af[i]  = *reinterpret_cast<const bf16x8*>(&As[(wm*64 + i*16 + mf)*32 + kq*8]);
#pragma unroll
    for (int j = 0; j < 4; j++)
      bfr[j] = *reinterpret_cast<const bf16x8*>(&Bs[(wn*64 + j*16 + mf)*32 + kq*8]);
#pragma unroll
    for (int i = 0; i < 4; i++)
#pragma unroll
      for (int j = 0; j < 4; j++)
        acc[i][j] = __builtin_amdgcn_mfma_f32_16x16x32_bf16(af[i], bfr[j], acc[i][j], 0, 0, 0);
    __syncthreads();
  }

  // epilogue: D[row=(lane>>4)*4+r][col=lane&15]
  const int rowq = (lane >> 4) * 4;
#pragma unroll
  for (int i = 0; i < 4; i++){
#pragma unroll
    for (int r = 0; r < 4; r++){
      int m  = m0 + wm*64 + i*16 + rowq + r;
      int nn = m >> 10, sp = m & 1023, oy = sp >> 5, ox = sp & 31;
#pragma unroll
      for (int j = 0; j < 4; j++){
        int co = n0 + wn*64 + j*16 + mf;
        float v = alpha * acc[i][j][r] + bias[co];
        if (res) v += bf2f(res[((size_t)((nn*34 + oy+1)*34 + ox+1))*256 + co]);
        if (out_mode == 2){
          outf[(size_t)m * N + co] = v;
        } else if (MODE == 3){
          int y2 = 2*oy + py + 1, x2 = 2*ox + px + 1;
          outb[((size_t)((nn*66 + y2)*66 + x2))*256 + co] = f2bf(v);
        } else {
          outb[((size_t)((nn*34 + oy+1)*34 + ox+1))*256 + co] = f2bf(v);
          if (out_mode == 1)
            outf[(size_t)nn*262144 + (size_t)co*1024 + oy*32 + ox] = v;
        }
      }
    }
  }
}

// ---------------- VQ argmin + gather -> z_q NCHW fp32 ----------------
__global__ __launch_bounds__(256) void k_vq_argmin(const float* __restrict__ scores,
    const float* __restrict__ cb, float* __restrict__ zq)
{
  __shared__ int best[32];
  __shared__ float Z[32*256];
  int tid = threadIdx.x, lane = tid & 63, wave = tid >> 6;
  int m0 = blockIdx.x * 32;
  int nn = m0 >> 10, y = (m0 >> 5) & 31;
  for (int rr = wave; rr < 32; rr += 4){
    const float* srow = scores + (size_t)(m0 + rr) * 512;
    float bv = 3.4e38f; int bk = 0;
    for (int k = lane; k < 512; k += 64){
      float v = srow[k];
      if (v < bv){ bv = v; bk = k; }
    }
    for (int off = 32; off; off >>= 1){
      float ov = __shfl_down(bv, off);
      int   ok = __shfl_down(bk, off);
      if (ov < bv || (ov == bv && ok < bk)){ bv = ov; bk = ok; }
    }
    if (lane == 0) best[rr] = bk;
  }
  __syncthreads();
  for (int rr = 0; rr < 32; rr++)
    Z[rr*256 + tid] = cb[best[rr]*256 + tid];
  __syncthreads();
  float* orow = zq + (size_t)nn*262144 + (size_t)tid*1024 + y*32;
#pragma unroll
  for (int x4 = 0; x4 < 8; x4++){
    float4 v;
    v.x = Z[(x4*4+0)*256 + tid];
    v.y = Z[(x4*4+1)*256 + tid];
    v.z = Z[(x4*4+2)*256 + tid];
    v.w = Z[(x4*4+3)*256 + tid];
    *(float4*)(orow + x4*4) = v;
  }
}

// ---------------- decoder conv2T: 256->3 k4 s2 p1, A64 bf16 NHWC halo -> x_rec fp32 NCHW ----------------
__global__ __launch_bounds__(256) void k_convt2(const bf16_t* __restrict__ in, const float* __restrict__ w,
    const float* __restrict__ bias, float* __restrict__ out)
{
  int cls = blockIdx.x >> 8;          // parity class (uniform per block -> scalar weight loads)
  int q   = blockIdx.x & 255;
  int py = cls >> 1, px = cls & 1;
  int idx = q*256 + threadIdx.x;      // < 65536
  int nn = idx >> 12, s = idx & 4095, oyh = s >> 6, oxh = s & 63;
  int oy = 2*oyh + py, ox = 2*oxh + px;
  float a0 = bias[0], a1 = bias[1], a2 = bias[2];
  for (int a = 0; a < 2; a++){
    for (int b = 0; b < 2; b++){
      int r = oyh + 1 - a + py, c = oxh + 1 - b + px;
      int ky = 2*a + 1 - py, kx = 2*b + 1 - px;
      const bf16_t* ip = in + ((size_t)((nn*66 + r)*66 + c))*256;
      const float* wp_ = w + ky*4 + kx;
      for (int ci8 = 0; ci8 < 32; ci8++){
        bf16x8 hv = *reinterpret_cast<const bf16x8*>(ip + ci8*8);
#pragma unroll
        for (int e = 0; e < 8; e++){
          int ci = ci8*8 + e;
          float f = bf2f(hv[e]);
          a0 += f * wp_[ci*48 +  0];
          a1 += f * wp_[ci*48 + 16];
          a2 += f * wp_[ci*48 + 32];
        }
      }
    }
  }
  size_t o = (size_t)nn*3*16384 + (size_t)oy*128 + ox;
  out[o]           = a0;
  out[o + 16384]   = a1;
  out[o + 32768]   = a2;
}

// ---------------- host ----------------
extern "C" void kernel_launch(void* const* d_in, const int* in_sizes, int n_in,
                              void* d_out, int out_size, void* d_ws, size_t ws_size,
                              hipStream_t stream)
{
  if (ws_size < (size_t)WS_NEEDED) return;

  const float* x       = (const float*)d_in[0];
  const float* ec1_w   = (const float*)d_in[1];
  const float* ec1_b   = (const float*)d_in[2];
  const float* ebn1_g  = (const float*)d_in[3];
  const float* ebn1_b  = (const float*)d_in[4];
  const float* ec2_w   = (const float*)d_in[5];
  const float* ec2_b   = (const float*)d_in[6];
  const float* rb_bn1_g= (const float*)d_in[7];
  const float* rb_bn1_b= (const float*)d_in[8];
  const float* rb_c3_w = (const float*)d_in[9];
  const float* rb_c3_b = (const float*)d_in[10];
  const float* rb_bn2_g= (const float*)d_in[11];
  const float* rb_bn2_b= (const float*)d_in[12];
  const float* rb_c1_w = (const float*)d_in[13];
  const float* rb_c1_b = (const float*)d_in[14];
  const float* dbn1_g  = (const float*)d_in[15];
  const float* dbn1_b  = (const float*)d_in[16];
  const float* dct1_w  = (const float*)d_in[17];
  const float* dct1_b  = (const float*)d_in[18];
  const float* dbn2_g  = (const float*)d_in[19];
  const float* dbn2_b  = (const float*)d_in[20];
  const float* dct2_w  = (const float*)d_in[21];
  const float* dct2_b  = (const float*)d_in[22];
  const float* codebook= (const float*)d_in[23];

  char* ws = (char*)d_ws;
  bf16_t* A64 = (bf16_t*)ws;
  bf16_t* SB0 = (bf16_t*)(ws + SB0_OFF);
  bf16_t* SB1 = (bf16_t*)(ws + SB0_OFF + 1*SB_BYTES);
  bf16_t* SB2 = (bf16_t*)(ws + SB0_OFF + 2*SB_BYTES);
  bf16_t* SB3 = (bf16_t*)(ws + SB0_OFF + 3*SB_BYTES);
  float*  stats = (float*)(ws + STATS_OFF);
  float*  cbn   = (float*)(ws + CBN_OFF);
  bf16_t* Wp    = (bf16_t*)(ws + WP_OFF);
  float*  scores= (float*)(ws + SCORES_OFF);

  float* xrec = (float*)d_out;
  float* zef  = xrec + 786432;
  float* zqf  = zef + 4194304;

  // prep: zero halo buffers + stats; repack weights; codebook norms
  k_zero  <<<dim3(17966), 256, 0, stream>>>((uint4*)ws, ZERO_BYTES/16);
  k_repack<<<dim3(18944), 256, 0, stream>>>(ec2_w, rb_c3_w, rb_c1_w, dct1_w, codebook, Wp);
  k_cbnorm<<<dim3(2),     256, 0, stream>>>(codebook, cbn);

  // encoder conv1 + bn/relu
  k_convin <<<dim3(4096),  256, 0, stream>>>(x, ec1_w, ec1_b, A64);
  k_bnstats<<<dim3(256),   256, 0, stream>>>(A64, stats, 6);
  k_bnapply<<<dim3(65536), 256, 0, stream>>>(A64, A64, stats, ebn1_g, ebn1_b, 6, 1.f/65536.f);
  // encoder conv2 (k4 s2): A64 -> SB0
  k_gemm<0><<<dim3(128,2,1), 256, 0, stream>>>(A64, Wp, ec2_b, nullptr, SB0, nullptr, 0, 1.f);

  auto launch_rb = [&](bf16_t* xin, bf16_t* xout, int i, int sA, int sB, float* zf){
    k_bnstats<<<dim3(256),   256, 0, stream>>>(xin, stats + sA*512, 5);
    k_bnapply<<<dim3(16384), 256, 0, stream>>>(xin, SB1, stats + sA*512,
                                               rb_bn1_g + i*256, rb_bn1_b + i*256, 5, 1.f/16384.f);
    k_gemm<1><<<dim3(128,2,1), 256, 0, stream>>>(SB1, Wp + WP_RB3(i), rb_c3_b + i*256,
                                                 nullptr, SB2, nullptr, 0, 1.f);
    k_bnstats<<<dim3(256),   256, 0, stream>>>(SB2, stats + sB*512, 5);
    k_bnapply<<<dim3(16384), 256, 0, stream>>>(SB2, SB2, stats + sB*512,
                                               rb_bn2_g + i*256, rb_bn2_b + i*256, 5, 1.f/16384.f);
    k_gemm<2><<<dim3(128,2,1), 256, 0, stream>>>(SB2, Wp + WP_RB1(i), rb_c1_b + i*256,
                                                 xin, xout, zf, zf ? 1 : 0, 1.f);
  };

  // resblocks 0,1 -> z_e (bf16 copy in SB0 + fp32 NCHW in d_out)
  launch_rb(SB0, SB3, 0, 1, 2, nullptr);
  launch_rb(SB3, SB0, 1, 3, 4, zef);

  // VQ: scores = |c|^2 - 2 z.c  (|z|^2 constant per row), then argmin + gather
  k_gemm<2><<<dim3(128,4,1), 256, 0, stream>>>(SB0, Wp + WP_CB, cbn, nullptr, nullptr, scores, 2, -2.f);
  k_vq_argmin<<<dim3(512), 256, 0, stream>>>(scores, codebook, zqf);

  // decoder resblocks 2,3
  launch_rb(SB0, SB3, 2, 5, 6, nullptr);
  launch_rb(SB3, SB0, 3, 7, 8, nullptr);

  // dbn1 + convT1 (parity-decomposed GEMM) -> A64
  k_bnstats<<<dim3(256),   256, 0, stream>>>(SB0, stats + 9*512, 5);
  k_bnapply<<<dim3(16384), 256, 0, stream>>>(SB0, SB0, stats + 9*512, dbn1_g, dbn1_b, 5, 1.f/16384.f);
  k_gemm<3><<<dim3(128,2,4), 256, 0, stream>>>(SB0, Wp + WP_CT, dct1_b, nullptr, A64, nullptr, 0, 1.f);

  // dbn2 + convT2 -> x_rec
  k_bnstats<<<dim3(256),   256, 0, stream>>>(A64, stats + 10*512, 6);
  k_bnapply<<<dim3(65536), 256, 0, stream>>>(A64, A64, stats + 10*512, dbn2_g, dbn2_b, 6, 1.f/65536.f);
  k_convt2<<<dim3(1024), 256, 0, stream>>>(A64, dct2_w, dct2_b, xrec);
}

// Round 2
// 872.368 us; speedup vs baseline: 1.4064x; 1.4064x over previous
//
#include <hip/hip_runtime.h>
#include <stdint.h>

typedef __bf16 bf16_t;
typedef __bf16 bf16x8 __attribute__((ext_vector_type(8)));
typedef float f32x4 __attribute__((ext_vector_type(4)));

#define DEVINL __device__ __forceinline__

DEVINL float bf2f(bf16_t h){ return (float)h; }
DEVINL bf16_t f2bf(float f){ return (bf16_t)f; }

// async 16B global -> LDS (wave-uniform LDS base + lane*16)
DEVINL void g2l16(const void* g, void* l){
  __builtin_amdgcn_global_load_lds(
      (const __attribute__((address_space(1))) uint32_t*)g,
      (__attribute__((address_space(3))) uint32_t*)l, 16, 0, 0);
}

// ---------------- workspace layout (bytes) ----------------
// A64 : [16][66][66][256] bf16 (64x64 + halo); scores (33.5MB fp32) OVERLAPS A64
//       (A64 is dead between encoder GEMM and convT1; halo re-zeroed after VQ)
// SB0..SB3 : [16][34][34][256] bf16 (32x32 + halo)
// stats: 11 slots x 512 f32
// Wp   : repacked bf16 weights (4,915,200 elems)
#define SB_BYTES    9469952
#define SB0_OFF     35684352
#define STATS_OFF   73564160
#define CBN_OFF     73586688
#define WP_OFF      73588736
#define WS_NEEDED   83419136
// Wp element offsets
#define WP_RB3(i) (1048576 + (i)*655360)
#define WP_RB1(i) (1048576 + (i)*655360 + 589824)
#define WP_CT     3670016
#define WP_CB     4718592
#define WP_CT2    4849664
#define WP_ELEMS  4915200

// ---------------- zero (stats) ----------------
__global__ __launch_bounds__(256) void k_zero(uint4* __restrict__ p, int n16){
  int i = blockIdx.x*256 + threadIdx.x;
  if (i < n16) p[i] = make_uint4(0,0,0,0);
}

// ---------------- zero halo strips of an NHWC halo buffer ----------------
__global__ __launch_bounds__(256) void k_zerohalo(bf16_t* __restrict__ buf, int IW, int total){
  int idx = blockIdx.x*256 + threadIdx.x;
  if (idx >= total) return;
  int g8 = idx & 31, r = idx >> 5;
  int H = 4*IW - 4;
  int nn = r / H, hp = r - nn*H;
  int y, x;
  if (hp < IW){ y = 0; x = hp; }
  else if (hp < 2*IW){ y = IW-1; x = hp - IW; }
  else {
    int h2 = hp - 2*IW;
    int side = h2 / (IW-2);
    int k = h2 - side*(IW-2);
    y = k + 1; x = side ? (IW-1) : 0;
  }
  bf16_t* p = buf + ((size_t)((nn*IW + y)*IW + x))*256 + g8*8;
  bf16x8 zv;
#pragma unroll
  for (int e = 0; e < 8; e++) zv[e] = f2bf(0.f);
  *(bf16x8*)p = zv;
}

// ---------------- weight repack (all layers + codebook + convT2 pad) ----------------
__global__ __launch_bounds__(256) void k_repack(
    const float* __restrict__ ec2_w, const float* __restrict__ rb_c3_w,
    const float* __restrict__ rb_c1_w, const float* __restrict__ dct1_w,
    const float* __restrict__ codebook, const float* __restrict__ dct2_w,
    bf16_t* __restrict__ wp)
{
  int idx = blockIdx.x*256 + threadIdx.x;
  if (idx >= WP_ELEMS) return;
  int l = idx; float v;
  if (l < 1048576) {                       // ec2: [t16][co][ci]
    int t = l>>16, co = (l>>8)&255, ci = l&255;
    v = ec2_w[co*4096 + ci*16 + t];
  } else {
    l -= 1048576;
    if (l < 2621440) {                     // resblocks
      int i = l / 655360;
      int r = l - i*655360;
      if (r < 589824) {                    // c3: [t9][co][ci]
        int t = r>>16, co = (r>>8)&255, ci = r&255;
        v = rb_c3_w[i*589824 + co*2304 + ci*9 + t];
      } else {                             // c1: [co][ci]
        r -= 589824;
        int co = r>>8, ci = r&255;
        v = rb_c1_w[i*65536 + co*256 + ci];
      }
    } else {
      l -= 2621440;
      if (l < 1048576) {                   // convT1: [par4][t4][co][ci]
        int z = l>>18, r = l&262143, t = r>>16, co = (r>>8)&255, ci = r&255;
        int py = z>>1, px = z&1, a = t>>1, b = t&1;
        int ky = 2*a + 1 - py, kx = 2*b + 1 - px;
        v = dct1_w[ci*4096 + co*16 + ky*4 + kx];
      } else {
        l -= 1048576;
        if (l < 131072) {                  // codebook [k][d]
          v = codebook[l];
        } else {                           // convT2: [par4][t4][co16(pad)][ci]
          l -= 131072;
          int z = l>>14, r = l&16383, t = r>>12, co = (r>>8)&15, ci = r&255;
          int py = z>>1, px = z&1, a = t>>1, b = t&1;
          int ky = 2*a + 1 - py, kx = 2*b + 1 - px;
          v = (co < 3) ? dct2_w[ci*48 + co*16 + ky*4 + kx] : 0.f;
        }
      }
    }
  }
  wp[idx] = f2bf(v);
}

// ---------------- codebook norms ----------------
__global__ __launch_bounds__(256) void k_cbnorm(const float* __restrict__ cb, float* __restrict__ out){
  int k = blockIdx.x*256 + threadIdx.x;
  float s = 0.f;
  for (int d = 0; d < 256; d++){ float v = cb[k*256 + d]; s += v*v; }
  out[k] = s;
}

// ---------------- encoder conv1: 3->256 k4 s2 p1 ----------------
__global__ __launch_bounds__(256) void k_convin(const float* __restrict__ x, const float* __restrict__ w,
    const float* __restrict__ bias, bf16_t* __restrict__ out)
{
  int co = threadIdx.x;
  float wr[48];
#pragma unroll
  for (int j = 0; j < 12; j++){
    float4 f = *(const float4*)(w + co*48 + j*4);
    wr[j*4+0]=f.x; wr[j*4+1]=f.y; wr[j*4+2]=f.z; wr[j*4+3]=f.w;
  }
  float bco = bias[co];
  int p0 = blockIdx.x * 16;
  for (int pi = 0; pi < 16; pi++){
    int p = p0 + pi;
    int nn = p >> 12, sp = p & 4095, oy = sp >> 6, ox = sp & 63;
    float acc = bco;
#pragma unroll
    for (int ky = 0; ky < 4; ky++){
      int iy = 2*oy + ky - 1;
      if (iy < 0 || iy > 127) continue;
#pragma unroll
      for (int kx = 0; kx < 4; kx++){
        int ix = 2*ox + kx - 1;
        if (ix < 0 || ix > 127) continue;
#pragma unroll
        for (int ci = 0; ci < 3; ci++)
          acc += x[((size_t)((nn*3+ci)*128 + iy))*128 + ix] * wr[ci*16 + ky*4 + kx];
      }
    }
    out[((size_t)((nn*66 + oy+1)*66 + ox+1))*256 + co] = f2bf(acc);
  }
}

// ---------------- BN stats: vectorized bf16x8, LDS-reduced ----------------
__global__ __launch_bounds__(256) void k_bnstats(const bf16_t* __restrict__ buf, float* __restrict__ stat, int hwlog)
{
  int HW = 1 << hwlog, IW = HW + 2;
  int P = 16 << (2*hwlog);
  int tid = threadIdx.x;
  int g8 = tid & 31, ps = tid >> 5;
  float s[8], s2[8];
#pragma unroll
  for (int e = 0; e < 8; e++){ s[e] = 0.f; s2[e] = 0.f; }
  for (int p = blockIdx.x*8 + ps; p < P; p += gridDim.x*8){
    int xx = p & (HW-1), yy = (p >> hwlog) & (HW-1), nn = p >> (2*hwlog);
    bf16x8 v = *(const bf16x8*)(buf + ((size_t)((nn*IW + yy+1)*IW + xx+1))*256 + g8*8);
#pragma unroll
    for (int e = 0; e < 8; e++){ float f = bf2f(v[e]); s[e] += f; s2[e] += f*f; }
  }
  __shared__ float red[8][256];
#pragma unroll
  for (int e = 0; e < 8; e++) red[ps][g8*8+e] = s[e];
  __syncthreads();
  { float t = 0.f;
    for (int q = 0; q < 8; q++) t += red[q][tid];
    atomicAdd(&stat[tid], t); }
  __syncthreads();
#pragma unroll
  for (int e = 0; e < 8; e++) red[ps][g8*8+e] = s2[e];
  __syncthreads();
  { float t = 0.f;
    for (int q = 0; q < 8; q++) t += red[q][tid];
    atomicAdd(&stat[256 + tid], t); }
}

// ---------------- BN apply + ReLU, vectorized (interior only) ----------------
__global__ __launch_bounds__(256) void k_bnapply(const bf16_t* __restrict__ in, bf16_t* __restrict__ out,
    const float* __restrict__ stat, const float* __restrict__ g, const float* __restrict__ b,
    int hwlog, float invc)
{
  int idx = blockIdx.x*256 + threadIdx.x;
  int g8 = idx & 31, p = idx >> 5;
  int HW = 1 << hwlog, IW = HW + 2;
  int xx = p & (HW-1), yy = (p >> hwlog) & (HW-1), nn = p >> (2*hwlog);
  size_t a = ((size_t)((nn*IW + yy+1)*IW + xx+1))*256 + g8*8;
  float4 sm0 = *(const float4*)(stat + g8*8),     sm1 = *(const float4*)(stat + g8*8 + 4);
  float4 sq0 = *(const float4*)(stat + 256 + g8*8), sq1 = *(const float4*)(stat + 256 + g8*8 + 4);
  float4 gg0 = *(const float4*)(g + g8*8),        gg1 = *(const float4*)(g + g8*8 + 4);
  float4 bb0 = *(const float4*)(b + g8*8),        bb1 = *(const float4*)(b + g8*8 + 4);
  float sm[8] = {sm0.x,sm0.y,sm0.z,sm0.w, sm1.x,sm1.y,sm1.z,sm1.w};
  float sq[8] = {sq0.x,sq0.y,sq0.z,sq0.w, sq1.x,sq1.y,sq1.z,sq1.w};
  float gv[8] = {gg0.x,gg0.y,gg0.z,gg0.w, gg1.x,gg1.y,gg1.z,gg1.w};
  float bv[8] = {bb0.x,bb0.y,bb0.z,bb0.w, bb1.x,bb1.y,bb1.z,bb1.w};
  bf16x8 v = *(const bf16x8*)(in + a);
  bf16x8 o;
#pragma unroll
  for (int e = 0; e < 8; e++){
    float mean = sm[e]*invc;
    float var  = sq[e]*invc - mean*mean;
    float sc = gv[e] * rsqrtf(var + 1e-5f);
    float sh = bv[e] - mean*sc;
    o[e] = f2bf(fmaxf(bf2f(v[e])*sc + sh, 0.f));
  }
  *(bf16x8*)(out + a) = o;
}

// ---------------- implicit-GEMM conv (MFMA bf16), TM=128, TN=64 (16 for MODE4), BK=32 ----------------
// MODE: 0=k4s2 enc (66-halo), 1=k3s1 (34), 2=k1 (34), 3=convT k4s2 par (34->66), 4=convT2 (66->NCHW fp32, N=16 pad)
template<int MODE>
__global__ __launch_bounds__(256) void k_gemm(
    const bf16_t* __restrict__ in, const bf16_t* __restrict__ wp,
    const float* __restrict__ bias, const bf16_t* __restrict__ res,
    bf16_t* __restrict__ outb, float* __restrict__ outf,
    int out_mode, float alpha)
{
  constexpr int TAPS = (MODE==0)?16:(MODE==1)?9:(MODE==2)?1:4;
  constexpr int TN   = (MODE==4)?16:64;
  constexpr int MI   = (MODE==4)?2:4;
  constexpr int MJ   = (MODE==4)?1:2;
  const int N = gridDim.y * TN;

  __shared__ __align__(16) bf16_t As[128*32];
  __shared__ __align__(16) bf16_t Bs[TN*32];

  const int tid  = threadIdx.x;
  const int lane = tid & 63;
  const int wave = tid >> 6;
  const int m0   = blockIdx.x * 128;
  const int n0   = blockIdx.y * TN;
  int py = 0, px = 0;
  const bf16_t* wpp = wp;
  if (MODE == 3){ py = blockIdx.z >> 1; px = blockIdx.z & 1; wpp += (size_t)blockIdx.z * 262144; }
  if (MODE == 4){ py = blockIdx.z >> 1; px = blockIdx.z & 1; wpp += (size_t)blockIdx.z * 16384; }

  int abase[2];
#pragma unroll
  for (int j = 0; j < 2; j++){
    int s = wave*128 + j*64 + lane;
    int ml = s >> 2, k8 = (s & 3) * 8;
    int m = m0 + ml;
    int pbase;
    if (MODE == 0){ int nn=m>>10, sp=m&1023, oy=sp>>5, ox=sp&31; pbase = (nn*66 + 2*oy)*66 + 2*ox; }
    else if (MODE == 3){ int nn=m>>10, sp=m&1023, oy=sp>>5, ox=sp&31; pbase = (nn*34 + oy+1+py)*34 + ox+1+px; }
    else if (MODE == 4){ int nn=m>>12, oyh=(m>>6)&63, oxh=m&63; pbase = (nn*66 + oyh+1+py)*66 + oxh+1+px; }
    else { int nn=m>>10, sp=m&1023, oy=sp>>5, ox=sp&31; pbase = (nn*34 + oy)*34 + ox; }
    abase[j] = pbase*256 + k8;
  }
  int bbase;
  {
    int s = (TN == 64) ? (wave*64 + lane) : lane;
    int ml = s >> 2, k8 = (s & 3) * 8;
    bbase = (n0 + ml)*256 + k8;
  }

  f32x4 acc[MI][MJ];
#pragma unroll
  for (int i = 0; i < MI; i++)
#pragma unroll
    for (int j = 0; j < MJ; j++) acc[i][j] = (f32x4){0.f,0.f,0.f,0.f};

  const int rowbase = (TN == 64) ? (wave >> 1)*64 : wave*32;
  const int colbase = (TN == 64) ? (wave & 1)*32 : 0;
  const int mf = lane & 15;
  const int kq = lane >> 4;

  for (int chunk = 0; chunk < TAPS*8; ++chunk){
    int t   = chunk >> 3;
    int ci0 = (chunk & 7) * 32;
    int toff;
    if (MODE == 0)      toff = (t >> 2)*66 + (t & 3);
    else if (MODE == 1){ int ky = t/3; toff = ky*34 + (t - ky*3); }
    else if (MODE == 2) toff = 35;
    else if (MODE == 3) toff = -((t >> 1)*34 + (t & 1));
    else                toff = -((t >> 1)*66 + (t & 1));
#pragma unroll
    for (int j = 0; j < 2; j++)
      g2l16(in + abase[j] + toff*256 + ci0, As + (wave*128 + j*64)*8);
    if (TN == 64)
      g2l16(wpp + (size_t)t*N*256 + bbase + ci0, Bs + wave*64*8);
    else if (wave == 0)
      g2l16(wpp + (size_t)t*N*256 + bbase + ci0, Bs);
    __syncthreads();

    bf16x8 af[MI], bfr[MJ];
#pragma unroll
    for (int i = 0; i < MI; i++)
      af[i]  = *reinterpret_cast<const bf16x8*>(&As[(rowbase + i*16 + mf)*32 + kq*8]);
#pragma unroll
    for (int j = 0; j < MJ; j++)
      bfr[j] = *reinterpret_cast<const bf16x8*>(&Bs[(colbase + j*16 + mf)*32 + kq*8]);
#pragma unroll
    for (int i = 0; i < MI; i++)
#pragma unroll
      for (int j = 0; j < MJ; j++)
        acc[i][j] = __builtin_amdgcn_mfma_f32_16x16x32_bf16(af[i], bfr[j], acc[i][j], 0, 0, 0);
    __syncthreads();
  }

  // epilogue: D[row=(lane>>4)*4+r][col=lane&15]
  const int rowq = (lane >> 4) * 4;
#pragma unroll
  for (int i = 0; i < MI; i++){
#pragma unroll
    for (int r = 0; r < 4; r++){
      int m = m0 + rowbase + i*16 + rowq + r;
      if (MODE == 4){
        int nn = m >> 12, oyh = (m >> 6) & 63, oxh = m & 63;
        int co = mf;
        if (co < 3){
          float v = acc[i][0][r] + bias[co];
          outf[(size_t)nn*49152 + (size_t)co*16384 + (2*oyh+py)*128 + (2*oxh+px)] = v;
        }
      } else {
        int nn = m >> 10, sp = m & 1023, oy = sp >> 5, ox = sp & 31;
#pragma unroll
        for (int j = 0; j < MJ; j++){
          int co = n0 + colbase + j*16 + mf;
          float v = alpha * acc[i][j][r] + bias[co];
          if (res) v += bf2f(res[((size_t)((nn*34 + oy+1)*34 + ox+1))*256 + co]);
          if (out_mode == 2){
            outf[(size_t)m * N + co] = v;
          } else if (MODE == 3){
            outb[((size_t)((nn*66 + 2*oy+py+1)*66 + 2*ox+px+1))*256 + co] = f2bf(v);
          } else {
            outb[((size_t)((nn*34 + oy+1)*34 + ox+1))*256 + co] = f2bf(v);
            if (out_mode == 1)
              outf[(size_t)nn*262144 + (size_t)co*1024 + oy*32 + ox] = v;
          }
        }
      }
    }
  }
}

// ---------------- VQ argmin + gather -> z_q NCHW fp32 ----------------
__global__ __launch_bounds__(256) void k_vq_argmin(const float* __restrict__ scores,
    const float* __restrict__ cb, float* __restrict__ zq)
{
  __shared__ int best[32];
  __shared__ float Z[32*256];
  int tid = threadIdx.x, lane = tid & 63, wave = tid >> 6;
  int m0 = blockIdx.x * 32;
  int nn = m0 >> 10, y = (m0 >> 5) & 31;
  for (int rr = wave; rr < 32; rr += 4){
    const float* srow = scores + (size_t)(m0 + rr) * 512;
    float bv = 3.4e38f; int bk = 0;
    for (int k = lane; k < 512; k += 64){
      float v = srow[k];
      if (v < bv){ bv = v; bk = k; }
    }
    for (int off = 32; off; off >>= 1){
      float ov = __shfl_down(bv, off);
      int   ok = __shfl_down(bk, off);
      if (ov < bv || (ov == bv && ok < bk)){ bv = ov; bk = ok; }
    }
    if (lane == 0) best[rr] = bk;
  }
  __syncthreads();
  for (int rr = 0; rr < 32; rr++)
    Z[rr*256 + tid] = cb[best[rr]*256 + tid];
  __syncthreads();
  float* orow = zq + (size_t)nn*262144 + (size_t)tid*1024 + y*32;
#pragma unroll
  for (int x4 = 0; x4 < 8; x4++){
    float4 v;
    v.x = Z[(x4*4+0)*256 + tid];
    v.y = Z[(x4*4+1)*256 + tid];
    v.z = Z[(x4*4+2)*256 + tid];
    v.w = Z[(x4*4+3)*256 + tid];
    *(float4*)(orow + x4*4) = v;
  }
}

// ---------------- host ----------------
extern "C" void kernel_launch(void* const* d_in, const int* in_sizes, int n_in,
                              void* d_out, int out_size, void* d_ws, size_t ws_size,
                              hipStream_t stream)
{
  if (ws_size < (size_t)WS_NEEDED) return;

  const float* x       = (const float*)d_in[0];
  const float* ec1_w   = (const float*)d_in[1];
  const float* ec1_b   = (const float*)d_in[2];
  const float* ebn1_g  = (const float*)d_in[3];
  const float* ebn1_b  = (const float*)d_in[4];
  const float* ec2_w   = (const float*)d_in[5];
  const float* ec2_b   = (const float*)d_in[6];
  const float* rb_bn1_g= (const float*)d_in[7];
  const float* rb_bn1_b= (const float*)d_in[8];
  const float* rb_c3_w = (const float*)d_in[9];
  const float* rb_c3_b = (const float*)d_in[10];
  const float* rb_bn2_g= (const float*)d_in[11];
  const float* rb_bn2_b= (const float*)d_in[12];
  const float* rb_c1_w = (const float*)d_in[13];
  const float* rb_c1_b = (const float*)d_in[14];
  const float* dbn1_g  = (const float*)d_in[15];
  const float* dbn1_b  = (const float*)d_in[16];
  const float* dct1_w  = (const float*)d_in[17];
  const float* dct1_b  = (const float*)d_in[18];
  const float* dbn2_g  = (const float*)d_in[19];
  const float* dbn2_b  = (const float*)d_in[20];
  const float* dct2_w  = (const float*)d_in[21];
  const float* dct2_b  = (const float*)d_in[22];
  const float* codebook= (const float*)d_in[23];

  char* ws = (char*)d_ws;
  bf16_t* A64 = (bf16_t*)ws;
  float*  scores = (float*)ws;                    // overlaps A64 (dead then)
  bf16_t* SB0 = (bf16_t*)(ws + SB0_OFF);
  bf16_t* SB1 = (bf16_t*)(ws + SB0_OFF + 1*SB_BYTES);
  bf16_t* SB2 = (bf16_t*)(ws + SB0_OFF + 2*SB_BYTES);
  bf16_t* SB3 = (bf16_t*)(ws + SB0_OFF + 3*SB_BYTES);
  float*  stats = (float*)(ws + STATS_OFF);
  float*  cbn   = (float*)(ws + CBN_OFF);
  bf16_t* Wp    = (bf16_t*)(ws + WP_OFF);

  float* xrec = (float*)d_out;
  float* zef  = xrec + 786432;
  float* zqf  = zef + 4194304;

  // prep
  k_zerohalo<<<dim3(521), 256, 0, stream>>>(A64, 66, 133120);
  k_zerohalo<<<dim3(264), 256, 0, stream>>>(SB0, 34, 67584);
  k_zerohalo<<<dim3(264), 256, 0, stream>>>(SB1, 34, 67584);
  k_zerohalo<<<dim3(264), 256, 0, stream>>>(SB2, 34, 67584);
  k_zerohalo<<<dim3(264), 256, 0, stream>>>(SB3, 34, 67584);
  k_zero  <<<dim3(6),     256, 0, stream>>>((uint4*)(ws + STATS_OFF), 1408);
  k_repack<<<dim3(19200), 256, 0, stream>>>(ec2_w, rb_c3_w, rb_c1_w, dct1_w, codebook, dct2_w, Wp);
  k_cbnorm<<<dim3(2),     256, 0, stream>>>(codebook, cbn);

  // encoder conv1 + bn/relu
  k_convin <<<dim3(4096), 256, 0, stream>>>(x, ec1_w, ec1_b, A64);
  k_bnstats<<<dim3(128),  256, 0, stream>>>(A64, stats, 6);
  k_bnapply<<<dim3(8192), 256, 0, stream>>>(A64, A64, stats, ebn1_g, ebn1_b, 6, 1.f/65536.f);
  // encoder conv2 (k4 s2): A64 -> SB0
  k_gemm<0><<<dim3(128,4,1), 256, 0, stream>>>(A64, Wp, ec2_b, nullptr, SB0, nullptr, 0, 1.f);

  auto launch_rb = [&](bf16_t* xin, bf16_t* xout, int i, int sA, int sB, float* zf){
    k_bnstats<<<dim3(128),  256, 0, stream>>>(xin, stats + sA*512, 5);
    k_bnapply<<<dim3(2048), 256, 0, stream>>>(xin, SB1, stats + sA*512,
                                              rb_bn1_g + i*256, rb_bn1_b + i*256, 5, 1.f/16384.f);
    k_gemm<1><<<dim3(128,4,1), 256, 0, stream>>>(SB1, Wp + WP_RB3(i), rb_c3_b + i*256,
                                                 nullptr, SB2, nullptr, 0, 1.f);
    k_bnstats<<<dim3(128),  256, 0, stream>>>(SB2, stats + sB*512, 5);
    k_bnapply<<<dim3(2048), 256, 0, stream>>>(SB2, SB2, stats + sB*512,
                                              rb_bn2_g + i*256, rb_bn2_b + i*256, 5, 1.f/16384.f);
    k_gemm<2><<<dim3(128,4,1), 256, 0, stream>>>(SB2, Wp + WP_RB1(i), rb_c1_b + i*256,
                                                 xin, xout, zf, zf ? 1 : 0, 1.f);
  };

  // resblocks 0,1 -> z_e
  launch_rb(SB0, SB3, 0, 1, 2, nullptr);
  launch_rb(SB3, SB0, 1, 3, 4, zef);

  // VQ: scores = |c|^2 - 2 z.c ; argmin + gather (scores overlaps A64)
  k_gemm<2><<<dim3(128,8,1), 256, 0, stream>>>(SB0, Wp + WP_CB, cbn, nullptr, nullptr, scores, 2, -2.f);
  k_vq_argmin<<<dim3(512), 256, 0, stream>>>(scores, codebook, zqf);
  k_zerohalo<<<dim3(521), 256, 0, stream>>>(A64, 66, 133120);   // restore halo clobbered by scores

  // decoder resblocks 2,3
  launch_rb(SB0, SB3, 2, 5, 6, nullptr);
  launch_rb(SB3, SB0, 3, 7, 8, nullptr);

  // dbn1 + convT1 (parity GEMM) -> A64
  k_bnstats<<<dim3(128),  256, 0, stream>>>(SB0, stats + 9*512, 5);
  k_bnapply<<<dim3(2048), 256, 0, stream>>>(SB0, SB0, stats + 9*512, dbn1_g, dbn1_b, 5, 1.f/16384.f);
  k_gemm<3><<<dim3(128,4,4), 256, 0, stream>>>(SB0, Wp + WP_CT, dct1_b, nullptr, A64, nullptr, 0, 1.f);

  // dbn2 + convT2 (parity GEMM, N=16 pad) -> x_rec
  k_bnstats<<<dim3(128),  256, 0, stream>>>(A64, stats + 10*512, 6);
  k_bnapply<<<dim3(8192), 256, 0, stream>>>(A64, A64, stats + 10*512, dbn2_g, dbn2_b, 6, 1.f/65536.f);
  k_gemm<4><<<dim3(512,1,4), 256, 0, stream>>>(A64, Wp + WP_CT2, dct2_b, nullptr, nullptr, xrec, 3, 1.f);
}

// Round 3
// 796.652 us; speedup vs baseline: 1.5401x; 1.0950x over previous
//
#include <hip/hip_runtime.h>
#include <stdint.h>

typedef __bf16 bf16_t;
typedef __bf16 bf16x8 __attribute__((ext_vector_type(8)));
typedef float f32x4 __attribute__((ext_vector_type(4)));

#define DEVINL __device__ __forceinline__

DEVINL float bf2f(bf16_t h){ return (float)h; }
DEVINL bf16_t f2bf(float f){ return (bf16_t)f; }

// async 16B global -> LDS (wave-uniform LDS base + lane*16)
DEVINL void g2l16(const void* g, void* l){
  __builtin_amdgcn_global_load_lds(
      (const __attribute__((address_space(1))) uint32_t*)g,
      (__attribute__((address_space(3))) uint32_t*)l, 16, 0, 0);
}

// ---------------- workspace layout (bytes) ----------------
// A64 : [16][66][66][256] bf16 (64x64 + halo); scores (33.5MB fp32) OVERLAPS A64
// SB0..SB3 : [16][34][34][256] bf16 (32x32 + halo)
// stats: 11 slots x 512 f32 (sum, sumsq per channel)
// Wp : repacked bf16 weights ; Xi : im2col of x [65536][64] bf16
#define SB_BYTES    9469952
#define SB0_OFF     35684352
#define STATS_OFF   73564160
#define CBN_OFF     73586688
#define WP_OFF      73588736
#define XI_OFF      83320832
#define WS_NEEDED   91709440
// Wp element offsets
#define WP_RB3(i) (1048576 + (i)*655360)
#define WP_RB1(i) (1048576 + (i)*655360 + 589824)
#define WP_CT     3670016
#define WP_CB     4718592
#define WP_EC1    4849664
#define WP_ELEMS  4866048

// ---------------- zero ----------------
__global__ __launch_bounds__(256) void k_zero(uint4* __restrict__ p, int n16){
  int i = blockIdx.x*256 + threadIdx.x;
  if (i < n16) p[i] = make_uint4(0,0,0,0);
}

// ---------------- zero halo strips of an NHWC halo buffer ----------------
__global__ __launch_bounds__(256) void k_zerohalo(bf16_t* __restrict__ buf, int IW, int total){
  int idx = blockIdx.x*256 + threadIdx.x;
  if (idx >= total) return;
  int g8 = idx & 31, r = idx >> 5;
  int H = 4*IW - 4;
  int nn = r / H, hp = r - nn*H;
  int y, x;
  if (hp < IW){ y = 0; x = hp; }
  else if (hp < 2*IW){ y = IW-1; x = hp - IW; }
  else {
    int h2 = hp - 2*IW;
    int side = h2 / (IW-2);
    int k = h2 - side*(IW-2);
    y = k + 1; x = side ? (IW-1) : 0;
  }
  bf16_t* p = buf + ((size_t)((nn*IW + y)*IW + x))*256 + g8*8;
  bf16x8 zv;
#pragma unroll
  for (int e = 0; e < 8; e++) zv[e] = f2bf(0.f);
  *(bf16x8*)p = zv;
}

// ---------------- weight repack ----------------
__global__ __launch_bounds__(256) void k_repack(
    const float* __restrict__ ec2_w, const float* __restrict__ rb_c3_w,
    const float* __restrict__ rb_c1_w, const float* __restrict__ dct1_w,
    const float* __restrict__ codebook, const float* __restrict__ ec1_w,
    bf16_t* __restrict__ wp)
{
  int idx = blockIdx.x*256 + threadIdx.x;
  if (idx >= WP_ELEMS) return;
  int l = idx; float v;
  if (l < 1048576) {                       // ec2: [t16][co][ci]
    int t = l>>16, co = (l>>8)&255, ci = l&255;
    v = ec2_w[co*4096 + ci*16 + t];
  } else {
    l -= 1048576;
    if (l < 2621440) {                     // resblocks
      int i = l / 655360;
      int r = l - i*655360;
      if (r < 589824) {                    // c3: [t9][co][ci]
        int t = r>>16, co = (r>>8)&255, ci = r&255;
        v = rb_c3_w[i*589824 + co*2304 + ci*9 + t];
      } else {                             // c1: [co][ci]
        r -= 589824;
        int co = r>>8, ci = r&255;
        v = rb_c1_w[i*65536 + co*256 + ci];
      }
    } else {
      l -= 2621440;
      if (l < 1048576) {                   // convT1: [par4][t4][co][ci]
        int z = l>>18, r = l&262143, t = r>>16, co = (r>>8)&255, ci = r&255;
        int py = z>>1, px = z&1, a = t>>1, b = t&1;
        int ky = 2*a + 1 - py, kx = 2*b + 1 - px;
        v = dct1_w[ci*4096 + co*16 + ky*4 + kx];
      } else {
        l -= 1048576;
        if (l < 131072) {                  // codebook [k][d]
          v = codebook[l];
        } else {                           // ec1 B: [co][64] (k = ci*16 + ky*4 + kx, pad 48..63)
          l -= 131072;
          int co = l>>6, k = l&63;
          v = (k < 48) ? ec1_w[co*48 + k] : 0.f;
        }
      }
    }
  }
  wp[idx] = f2bf(v);
}

// ---------------- codebook norms ----------------
__global__ __launch_bounds__(256) void k_cbnorm(const float* __restrict__ cb, float* __restrict__ out){
  int k = blockIdx.x*256 + threadIdx.x;
  float s = 0.f;
  for (int d = 0; d < 256; d++){ float v = cb[k*256 + d]; s += v*v; }
  out[k] = s;
}

// ---------------- im2col for conv1: x fp32 NCHW -> Xi [65536][64] bf16 ----------------
__global__ __launch_bounds__(256) void k_im2col(const float* __restrict__ x, bf16_t* __restrict__ Xi){
  int m = blockIdx.x*256 + threadIdx.x;
  int nn = m >> 12, oy = (m >> 6) & 63, ox = m & 63;
  bf16_t row[64];
#pragma unroll
  for (int k = 48; k < 64; k++) row[k] = f2bf(0.f);
#pragma unroll
  for (int ci = 0; ci < 3; ci++)
#pragma unroll
    for (int ky = 0; ky < 4; ky++){
      int iy = 2*oy + ky - 1;
      bool yok = (unsigned)iy < 128u;
#pragma unroll
      for (int kx = 0; kx < 4; kx++){
        int ix = 2*ox + kx - 1;
        float v = (yok && (unsigned)ix < 128u) ? x[((size_t)((nn*3+ci)*128 + iy))*128 + ix] : 0.f;
        row[ci*16 + ky*4 + kx] = f2bf(v);
      }
    }
#pragma unroll
  for (int u = 0; u < 8; u++){
    bf16x8 o;
#pragma unroll
    for (int e = 0; e < 8; e++) o[e] = row[u*8+e];
    *(bf16x8*)(Xi + (size_t)m*64 + u*8) = o;
  }
}

// ---------------- BN apply + ReLU, vectorized (interior only) ----------------
__global__ __launch_bounds__(256) void k_bnapply(const bf16_t* __restrict__ in, bf16_t* __restrict__ out,
    const float* __restrict__ stat, const float* __restrict__ g, const float* __restrict__ b,
    int hwlog, float invc)
{
  int idx = blockIdx.x*256 + threadIdx.x;
  int g8 = idx & 31, p = idx >> 5;
  int HW = 1 << hwlog, IW = HW + 2;
  int xx = p & (HW-1), yy = (p >> hwlog) & (HW-1), nn = p >> (2*hwlog);
  size_t a = ((size_t)((nn*IW + yy+1)*IW + xx+1))*256 + g8*8;
  float sm[8], sq[8], gv[8], bv[8];
#pragma unroll
  for (int e = 0; e < 8; e += 4){
    *(float4*)(sm+e) = *(const float4*)(stat + g8*8 + e);
    *(float4*)(sq+e) = *(const float4*)(stat + 256 + g8*8 + e);
    *(float4*)(gv+e) = *(const float4*)(g + g8*8 + e);
    *(float4*)(bv+e) = *(const float4*)(b + g8*8 + e);
  }
  bf16x8 v = *(const bf16x8*)(in + a);
  bf16x8 o;
#pragma unroll
  for (int e = 0; e < 8; e++){
    float mean = sm[e]*invc;
    float var  = sq[e]*invc - mean*mean;
    float sc = gv[e] * rsqrtf(var + 1e-5f);
    float sh = bv[e] - mean*sc;
    o[e] = f2bf(fmaxf(bf2f(v[e])*sc + sh, 0.f));
  }
  *(bf16x8*)(out + a) = o;
}

// ---------------- implicit-GEMM conv (MFMA bf16), TM=128, TN=64, BK=64 (XOR-swizzled LDS) ---------
// MODE: 0=k4s2 enc (66-halo), 1=k3s1 (34), 2=k1 (34), 3=convT k4s2 par (34->66), 5=im2col flat K=64
template<int MODE>
__global__ __launch_bounds__(256) void k_gemm(
    const bf16_t* __restrict__ in, const bf16_t* __restrict__ wp,
    const float* __restrict__ bias, const bf16_t* __restrict__ res,
    bf16_t* __restrict__ outb, float* __restrict__ outf,
    float* __restrict__ stat, int out_mode, float alpha)
{
  constexpr int TAPS = (MODE==0)?16:(MODE==1)?9:(MODE==2)?1:(MODE==3)?4:1;
  constexpr int CHUNKS = (MODE==5)?1:TAPS*4;
  const int N = gridDim.y * 64;

  __shared__ __align__(16) bf16_t As[128*64];
  __shared__ __align__(16) bf16_t Bs[64*64];
  __shared__ float s_sum[64], s_sum2[64];

  const int tid  = threadIdx.x;
  const int lane = tid & 63;
  const int wave = tid >> 6;
  const int m0   = blockIdx.x * 128;
  const int n0   = blockIdx.y * 64;
  int py = 0, px = 0;
  const bf16_t* wpp = wp;
  if (MODE == 3){ py = blockIdx.z >> 1; px = blockIdx.z & 1; wpp += (size_t)blockIdx.z * 262144; }

  // A staging slots: s = j*256 + wave*64 + lane ; row = s>>3 ; LDS unit = s&7 holds
  // global unit (s&7)^(row&7)  (XOR swizzle -> conflict-free ds_read_b128 later)
  int abase[4];
#pragma unroll
  for (int j = 0; j < 4; j++){
    int s = j*256 + wave*64 + lane;
    int row = s >> 3, ug = (s & 7) ^ (row & 7);
    int m = m0 + row;
    int pbase;
    if (MODE == 0){ int nn=m>>10, sp=m&1023, oy=sp>>5, ox=sp&31; pbase = (nn*66 + 2*oy)*66 + 2*ox; }
    else if (MODE == 3){ int nn=m>>10, sp=m&1023, oy=sp>>5, ox=sp&31; pbase = (nn*34 + oy+1+py)*34 + ox+1+px; }
    else if (MODE == 5){ pbase = 0; }
    else { int nn=m>>10, sp=m&1023, oy=sp>>5, ox=sp&31; pbase = (nn*34 + oy)*34 + ox; }
    abase[j] = (MODE==5) ? (m*64 + ug*8) : (pbase*256 + ug*8);
  }
  int bbase[2];
#pragma unroll
  for (int j = 0; j < 2; j++){
    int s = j*256 + wave*64 + lane;
    int row = s >> 3, ug = (s & 7) ^ (row & 7);
    bbase[j] = (MODE==5) ? ((n0+row)*64 + ug*8) : ((n0+row)*256 + ug*8);
  }

  f32x4 acc[4][2];
#pragma unroll
  for (int i = 0; i < 4; i++)
#pragma unroll
    for (int j = 0; j < 2; j++) acc[i][j] = (f32x4){0.f,0.f,0.f,0.f};

  const int rowbase = (wave >> 1) * 64;
  const int colbase = (wave & 1) * 32;
  const int mf = lane & 15;
  const int kq = lane >> 4;

  for (int c = 0; c < CHUNKS; ++c){
    int t = (MODE==5) ? 0 : (c >> 2);
    int koff;
    if (MODE == 0)      koff = ((t >> 2)*66 + (t & 3))*256 + ((c&3)<<6);
    else if (MODE == 1){ int ky = t/3; koff = (ky*34 + (t - ky*3))*256 + ((c&3)<<6); }
    else if (MODE == 2) koff = 35*256 + ((c&3)<<6);
    else if (MODE == 3) koff = -((t >> 1)*34 + (t & 1))*256 + ((c&3)<<6);
    else                koff = 0;
    size_t bko = (MODE==5) ? 0 : ((size_t)t*N*256 + ((c&3)<<6));
#pragma unroll
    for (int j = 0; j < 4; j++)
      g2l16(in + abase[j] + koff, As + (j*256 + wave*64)*8);
#pragma unroll
    for (int j = 0; j < 2; j++)
      g2l16(wpp + bko + bbase[j], Bs + (j*256 + wave*64)*8);
    __syncthreads();

#pragma unroll
    for (int kk = 0; kk < 2; kk++){
      bf16x8 af[4], bfr[2];
#pragma unroll
      for (int i = 0; i < 4; i++){
        int rr = rowbase + i*16 + mf;
        af[i] = *reinterpret_cast<const bf16x8*>(&As[rr*64 + (((kk*4+kq) ^ (rr&7))<<3)]);
      }
#pragma unroll
      for (int j = 0; j < 2; j++){
        int rr = colbase + j*16 + mf;
        bfr[j] = *reinterpret_cast<const bf16x8*>(&Bs[rr*64 + (((kk*4+kq) ^ (rr&7))<<3)]);
      }
#pragma unroll
      for (int i = 0; i < 4; i++)
#pragma unroll
        for (int j = 0; j < 2; j++)
          acc[i][j] = __builtin_amdgcn_mfma_f32_16x16x32_bf16(af[i], bfr[j], acc[i][j], 0, 0, 0);
    }
    __syncthreads();
  }

  // epilogue: D[row=(lane>>4)*4+r][col=lane&15] ; fused per-channel sum/sumsq stats
  float psum[2] = {0.f, 0.f}, psum2[2] = {0.f, 0.f};
  const int rowq = (lane >> 4) * 4;
#pragma unroll
  for (int i = 0; i < 4; i++){
#pragma unroll
    for (int r = 0; r < 4; r++){
      int m = m0 + rowbase + i*16 + rowq + r;
      int nn, oy, ox;
      if (MODE == 5){ nn = m >> 12; oy = (m >> 6) & 63; ox = m & 63; }
      else { nn = m >> 10; oy = (m >> 5) & 31; ox = m & 31; }
#pragma unroll
      for (int j = 0; j < 2; j++){
        int co = n0 + colbase + j*16 + mf;
        float v = alpha * acc[i][j][r] + bias[co];
        if (res) v += bf2f(res[((size_t)((nn*34 + oy+1)*34 + ox+1))*256 + co]);
        psum[j] += v; psum2[j] += v*v;
        if (out_mode == 2){
          outf[(size_t)m * N + co] = v;
        } else if (MODE == 3){
          outb[((size_t)((nn*66 + 2*oy+py+1)*66 + 2*ox+px+1))*256 + co] = f2bf(v);
        } else if (MODE == 5){
          outb[((size_t)((nn*66 + oy+1)*66 + ox+1))*256 + co] = f2bf(v);
        } else {
          outb[((size_t)((nn*34 + oy+1)*34 + ox+1))*256 + co] = f2bf(v);
          if (out_mode == 1)
            outf[(size_t)nn*262144 + (size_t)co*1024 + oy*32 + ox] = v;
        }
      }
    }
  }
  if (stat){
    if (tid < 64){ s_sum[tid] = 0.f; s_sum2[tid] = 0.f; }
    __syncthreads();
#pragma unroll
    for (int j = 0; j < 2; j++){
      int cl = colbase + j*16 + mf;
      atomicAdd(&s_sum[cl], psum[j]);
      atomicAdd(&s_sum2[cl], psum2[j]);
    }
    __syncthreads();
    if (tid < 64){
      atomicAdd(&stat[n0 + tid], s_sum[tid]);
      atomicAdd(&stat[256 + n0 + tid], s_sum2[tid]);
    }
  }
}

// ---------------- VQ argmin + gather -> z_q NCHW fp32 ----------------
__global__ __launch_bounds__(256) void k_vq_argmin(const float* __restrict__ scores,
    const float* __restrict__ cb, float* __restrict__ zq)
{
  __shared__ int best[32];
  __shared__ float Z[32*256];
  int tid = threadIdx.x, lane = tid & 63, wave = tid >> 6;
  int m0 = blockIdx.x * 32;
  int nn = m0 >> 10, y = (m0 >> 5) & 31;
  for (int rr = wave; rr < 32; rr += 4){
    const float* srow = scores + (size_t)(m0 + rr) * 512;
    float bv = 3.4e38f; int bk = 0;
    for (int k = lane; k < 512; k += 64){
      float v = srow[k];
      if (v < bv){ bv = v; bk = k; }
    }
    for (int off = 32; off; off >>= 1){
      float ov = __shfl_down(bv, off);
      int   ok = __shfl_down(bk, off);
      if (ov < bv || (ov == bv && ok < bk)){ bv = ov; bk = ok; }
    }
    if (lane == 0) best[rr] = bk;
  }
  __syncthreads();
  for (int rr = 0; rr < 32; rr++)
    Z[rr*256 + tid] = cb[best[rr]*256 + tid];
  __syncthreads();
  float* orow = zq + (size_t)nn*262144 + (size_t)tid*1024 + y*32;
#pragma unroll
  for (int x4 = 0; x4 < 8; x4++){
    float4 v;
    v.x = Z[(x4*4+0)*256 + tid];
    v.y = Z[(x4*4+1)*256 + tid];
    v.z = Z[(x4*4+2)*256 + tid];
    v.w = Z[(x4*4+3)*256 + tid];
    *(float4*)(orow + x4*4) = v;
  }
}

// ---------------- decoder convT2: direct, dbn2 BN+ReLU fused into loads ----------------
__global__ __launch_bounds__(256) void k_convt2(const bf16_t* __restrict__ A, const float* __restrict__ w,
    const float* __restrict__ bias, const float* __restrict__ stat,
    const float* __restrict__ g, const float* __restrict__ b, float* __restrict__ out)
{
  __shared__ float sc_s[256], sh_s[256];
  int tid = threadIdx.x;
  {
    float mean = stat[tid] * (1.f/65536.f);
    float var  = stat[256+tid] * (1.f/65536.f) - mean*mean;
    float s = g[tid] * rsqrtf(var + 1e-5f);
    sc_s[tid] = s; sh_s[tid] = b[tid] - mean*s;
  }
  __syncthreads();
  int m = blockIdx.x*256 + tid;
  int nn = m >> 12, oyh = (m >> 6) & 63, oxh = m & 63;
  float acc[4][3];
#pragma unroll
  for (int p = 0; p < 4; p++)
#pragma unroll
    for (int co = 0; co < 3; co++) acc[p][co] = bias[co];

  // per-pixel validity & base pointers (halo = conv zero-padding: skip, do NOT bn it)
  const bf16_t* ipp[9]; bool vv[9];
#pragma unroll
  for (int dy = 0; dy < 3; dy++)
#pragma unroll
    for (int dx = 0; dx < 3; dx++){
      int h = oyh + dy, ww = oxh + dx;
      vv[dy*3+dx] = (h >= 1 && h <= 64 && ww >= 1 && ww <= 64);
      ipp[dy*3+dx] = A + ((size_t)((nn*66 + h)*66 + ww))*256;
    }

  static const int cnt_[3] = {1,2,1};
  static const int pys_[3][2] = {{0,0},{0,1},{1,0}};
  static const int kys_[3][2] = {{3,0},{1,2},{0,0}};

  for (int c8 = 0; c8 < 32; c8++){
    float sc[8], sh[8];
#pragma unroll
    for (int e = 0; e < 8; e += 4){
      *(float4*)(sc+e) = *(const float4*)(sc_s + c8*8 + e);
      *(float4*)(sh+e) = *(const float4*)(sh_s + c8*8 + e);
    }
#pragma unroll
    for (int dy = 0; dy < 3; dy++)
#pragma unroll
      for (int dx = 0; dx < 3; dx++){
        if (!vv[dy*3+dx]) continue;
        bf16x8 hv = *reinterpret_cast<const bf16x8*>(ipp[dy*3+dx] + c8*8);
#pragma unroll
        for (int e = 0; e < 8; e++){
          int ci = c8*8 + e;
          float f = fmaxf(bf2f(hv[e])*sc[e] + sh[e], 0.f);
#pragma unroll
          for (int iy = 0; iy < cnt_[dy]; iy++){
            int py = pys_[dy][iy], ky = kys_[dy][iy];
#pragma unroll
            for (int ix = 0; ix < cnt_[dx]; ix++){
              int px = pys_[dx][ix], kx = kys_[dx][ix];
#pragma unroll
              for (int co = 0; co < 3; co++)
                acc[py*2+px][co] += f * w[ci*48 + co*16 + ky*4 + kx];
            }
          }
        }
      }
  }
#pragma unroll
  for (int py = 0; py < 2; py++)
#pragma unroll
    for (int px = 0; px < 2; px++)
#pragma unroll
      for (int co = 0; co < 3; co++)
        out[(size_t)nn*49152 + (size_t)co*16384 + (size_t)(2*oyh+py)*128 + (2*oxh+px)] = acc[py*2+px][co];
}

// ---------------- host ----------------
extern "C" void kernel_launch(void* const* d_in, const int* in_sizes, int n_in,
                              void* d_out, int out_size, void* d_ws, size_t ws_size,
                              hipStream_t stream)
{
  if (ws_size < (size_t)WS_NEEDED) return;

  const float* x       = (const float*)d_in[0];
  const float* ec1_w   = (const float*)d_in[1];
  const float* ec1_b   = (const float*)d_in[2];
  const float* ebn1_g  = (const float*)d_in[3];
  const float* ebn1_b  = (const float*)d_in[4];
  const float* ec2_w   = (const float*)d_in[5];
  const float* ec2_b   = (const float*)d_in[6];
  const float* rb_bn1_g= (const float*)d_in[7];
  const float* rb_bn1_b= (const float*)d_in[8];
  const float* rb_c3_w = (const float*)d_in[9];
  const float* rb_c3_b = (const float*)d_in[10];
  const float* rb_bn2_g= (const float*)d_in[11];
  const float* rb_bn2_b= (const float*)d_in[12];
  const float* rb_c1_w = (const float*)d_in[13];
  const float* rb_c1_b = (const float*)d_in[14];
  const float* dbn1_g  = (const float*)d_in[15];
  const float* dbn1_b  = (const float*)d_in[16];
  const float* dct1_w  = (const float*)d_in[17];
  const float* dct1_b  = (const float*)d_in[18];
  const float* dbn2_g  = (const float*)d_in[19];
  const float* dbn2_b  = (const float*)d_in[20];
  const float* dct2_w  = (const float*)d_in[21];
  const float* dct2_b  = (const float*)d_in[22];
  const float* codebook= (const float*)d_in[23];

  char* ws = (char*)d_ws;
  bf16_t* A64 = (bf16_t*)ws;
  float*  scores = (float*)ws;                    // overlaps A64 (A64 dead then)
  bf16_t* SB0 = (bf16_t*)(ws + SB0_OFF);
  bf16_t* SB1 = (bf16_t*)(ws + SB0_OFF + 1*SB_BYTES);
  bf16_t* SB2 = (bf16_t*)(ws + SB0_OFF + 2*SB_BYTES);
  bf16_t* SB3 = (bf16_t*)(ws + SB0_OFF + 3*SB_BYTES);
  float*  stats = (float*)(ws + STATS_OFF);
  float*  cbn   = (float*)(ws + CBN_OFF);
  bf16_t* Wp    = (bf16_t*)(ws + WP_OFF);
  bf16_t* Xi    = (bf16_t*)(ws + XI_OFF);

  float* xrec = (float*)d_out;
  float* zef  = xrec + 786432;
  float* zqf  = zef + 4194304;

  // prep
  k_zerohalo<<<dim3(521), 256, 0, stream>>>(A64, 66, 133120);
  k_zerohalo<<<dim3(264), 256, 0, stream>>>(SB0, 34, 67584);
  k_zerohalo<<<dim3(264), 256, 0, stream>>>(SB1, 34, 67584);
  k_zerohalo<<<dim3(264), 256, 0, stream>>>(SB2, 34, 67584);
  k_zerohalo<<<dim3(264), 256, 0, stream>>>(SB3, 34, 67584);
  k_zero  <<<dim3(6),     256, 0, stream>>>((uint4*)(ws + STATS_OFF), 1408);
  k_repack<<<dim3(19008), 256, 0, stream>>>(ec2_w, rb_c3_w, rb_c1_w, dct1_w, codebook, ec1_w, Wp);
  k_cbnorm<<<dim3(2),     256, 0, stream>>>(codebook, cbn);

  // encoder conv1 (im2col + GEMM, stats slot0 fused) + ebn1 apply
  k_im2col<<<dim3(256), 256, 0, stream>>>(x, Xi);
  k_gemm<5><<<dim3(512,4,1), 256, 0, stream>>>(Xi, Wp + WP_EC1, ec1_b, nullptr, A64, nullptr,
                                               stats, 0, 1.f);
  k_bnapply<<<dim3(8192), 256, 0, stream>>>(A64, A64, stats, ebn1_g, ebn1_b, 6, 1.f/65536.f);
  // encoder conv2 (k4 s2): A64 -> SB0, stats slot1 (rb0.bn1)
  k_gemm<0><<<dim3(128,4,1), 256, 0, stream>>>(A64, Wp, ec2_b, nullptr, SB0, nullptr,
                                               stats + 1*512, 0, 1.f);

  auto launch_rb = [&](bf16_t* xin, bf16_t* xout, int i, int sIn, int sMid, int sOut, float* zf){
    k_bnapply<<<dim3(2048), 256, 0, stream>>>(xin, SB1, stats + sIn*512,
                                              rb_bn1_g + i*256, rb_bn1_b + i*256, 5, 1.f/16384.f);
    k_gemm<1><<<dim3(128,4,1), 256, 0, stream>>>(SB1, Wp + WP_RB3(i), rb_c3_b + i*256,
                                                 nullptr, SB2, nullptr, stats + sMid*512, 0, 1.f);
    k_bnapply<<<dim3(2048), 256, 0, stream>>>(SB2, SB2, stats + sMid*512,
                                              rb_bn2_g + i*256, rb_bn2_b + i*256, 5, 1.f/16384.f);
    k_gemm<2><<<dim3(128,4,1), 256, 0, stream>>>(SB2, Wp + WP_RB1(i), rb_c1_b + i*256,
                                                 xin, xout, zf, stats + sOut*512, zf ? 1 : 0, 1.f);
  };

  // resblocks 0,1 -> z_e
  launch_rb(SB0, SB3, 0, 1, 2, 3, nullptr);
  launch_rb(SB3, SB0, 1, 3, 4, 5, zef);

  // VQ: scores = |c|^2 - 2 z.c ; argmin + gather (scores overlaps A64)
  k_gemm<2><<<dim3(128,8,1), 256, 0, stream>>>(SB0, Wp + WP_CB, cbn, nullptr, nullptr, scores,
                                               nullptr, 2, -2.f);
  k_vq_argmin<<<dim3(512), 256, 0, stream>>>(scores, codebook, zqf);
  k_zerohalo<<<dim3(521), 256, 0, stream>>>(A64, 66, 133120);   // restore halo clobbered by scores

  // decoder resblocks 2,3
  launch_rb(SB0, SB3, 2, 5, 6, 7, nullptr);
  launch_rb(SB3, SB0, 3, 7, 8, 9, nullptr);

  // dbn1 apply + convT1 (parity GEMM, stats slot10 = dbn2 stats) -> A64
  k_bnapply<<<dim3(2048), 256, 0, stream>>>(SB0, SB0, stats + 9*512, dbn1_g, dbn1_b, 5, 1.f/16384.f);
  k_gemm<3><<<dim3(128,4,4), 256, 0, stream>>>(SB0, Wp + WP_CT, dct1_b, nullptr, A64, nullptr,
                                               stats + 10*512, 0, 1.f);

  // convT2 direct with fused dbn2 BN+ReLU -> x_rec
  k_convt2<<<dim3(256), 256, 0, stream>>>(A64, dct2_w, dct2_b, stats + 10*512, dbn2_g, dbn2_b, xrec);
}

// Round 4
// 733.819 us; speedup vs baseline: 1.6720x; 1.0856x over previous
//
#include <hip/hip_runtime.h>
#include <stdint.h>

typedef __bf16 bf16_t;
typedef __bf16 bf16x8 __attribute__((ext_vector_type(8)));
typedef float f32x4 __attribute__((ext_vector_type(4)));

#define DEVINL __device__ __forceinline__

DEVINL float bf2f(bf16_t h){ return (float)h; }
DEVINL bf16_t f2bf(float f){ return (bf16_t)f; }

// async 16B global -> LDS (wave-uniform LDS base + lane*16)
DEVINL void g2l16(const void* g, void* l){
  __builtin_amdgcn_global_load_lds(
      (const __attribute__((address_space(1))) uint32_t*)g,
      (__attribute__((address_space(3))) uint32_t*)l, 16, 0, 0);
}

// ---------------- workspace layout (bytes) ----------------
// A64 : [16][66][66][256] bf16 (64x64 + halo); scores (33.5MB fp32) OVERLAPS A64
// SB0..SB3 : [16][34][34][256] bf16 (32x32 + halo); P (16.8MB fp32) OVERLAPS SB1+SB2
// stats: 11 slots x 512 f32 ; Wp : repacked bf16 weights ; Xi : im2col [65536][64] bf16
#define SB_BYTES    9469952
#define SB0_OFF     35684352
#define STATS_OFF   73564160
#define CBN_OFF     73586688
#define WP_OFF      73588736
#define XI_OFF      83353600
#define WS_NEEDED   91742208
// Wp element offsets
#define WP_RB3(i) (1048576 + (i)*655360)
#define WP_RB1(i) (1048576 + (i)*655360 + 589824)
#define WP_CT     3670016
#define WP_CB     4718592
#define WP_EC1    4849664
#define WP_CT2    4866048
#define WP_ELEMS  4882432

// ---------------- prep: zero all halos + stats in ONE kernel ----------------
DEVINL void zerohalo_one(bf16_t* buf, int IW, int idx){
  int g8 = idx & 31, r = idx >> 5;
  int H = 4*IW - 4;
  int nn = r / H, hp = r - nn*H;
  int y, x;
  if (hp < IW){ y = 0; x = hp; }
  else if (hp < 2*IW){ y = IW-1; x = hp - IW; }
  else {
    int h2 = hp - 2*IW;
    int side = h2 / (IW-2);
    int k = h2 - side*(IW-2);
    y = k + 1; x = side ? (IW-1) : 0;
  }
  bf16_t* p = buf + ((size_t)((nn*IW + y)*IW + x))*256 + g8*8;
  bf16x8 zv;
#pragma unroll
  for (int e = 0; e < 8; e++) zv[e] = f2bf(0.f);
  *(bf16x8*)p = zv;
}

__global__ __launch_bounds__(256) void k_prep(bf16_t* __restrict__ A64, bf16_t* __restrict__ SB,
                                              uint4* __restrict__ statz){
  int b = blockIdx.x, t = threadIdx.x;
  if (b < 521){
    int idx = b*256 + t;
    if (idx < 133120) zerohalo_one(A64, 66, idx);
  } else if (b < 1577){
    int r = b - 521;
    int buf = r / 264, li = r - buf*264;
    int idx = li*256 + t;
    if (idx < 67584) zerohalo_one(SB + (size_t)buf*(SB_BYTES/2), 34, idx);
  } else {
    int i = (b - 1577)*256 + t;
    if (i < 1408) statz[i] = make_uint4(0,0,0,0);
  }
}

// ---------------- weight repack + codebook norms (fused) ----------------
__global__ __launch_bounds__(256) void k_repack(
    const float* __restrict__ ec2_w, const float* __restrict__ rb_c3_w,
    const float* __restrict__ rb_c1_w, const float* __restrict__ dct1_w,
    const float* __restrict__ codebook, const float* __restrict__ ec1_w,
    const float* __restrict__ dct2_w, bf16_t* __restrict__ wp, float* __restrict__ cbn)
{
  int idx = blockIdx.x*256 + threadIdx.x;
  if (idx >= WP_ELEMS){
    int k = idx - WP_ELEMS;        // 512 codebook-norm slots
    if (k < 512){
      float s = 0.f;
      for (int d = 0; d < 256; d++){ float v = codebook[k*256 + d]; s += v*v; }
      cbn[k] = s;
    }
    return;
  }
  int l = idx; float v;
  if (l < 1048576) {                       // ec2: [t16][co][ci]
    int t = l>>16, co = (l>>8)&255, ci = l&255;
    v = ec2_w[co*4096 + ci*16 + t];
  } else {
    l -= 1048576;
    if (l < 2621440) {                     // resblocks
      int i = l / 655360;
      int r = l - i*655360;
      if (r < 589824) {                    // c3: [t9][co][ci]
        int t = r>>16, co = (r>>8)&255, ci = r&255;
        v = rb_c3_w[i*589824 + co*2304 + ci*9 + t];
      } else {                             // c1: [co][ci]
        r -= 589824;
        int co = r>>8, ci = r&255;
        v = rb_c1_w[i*65536 + co*256 + ci];
      }
    } else {
      l -= 2621440;
      if (l < 1048576) {                   // convT1: [par4][t4][co][ci]
        int z = l>>18, r = l&262143, t = r>>16, co = (r>>8)&255, ci = r&255;
        int py = z>>1, px = z&1, a = t>>1, b = t&1;
        int ky = 2*a + 1 - py, kx = 2*b + 1 - px;
        v = dct1_w[ci*4096 + co*16 + ky*4 + kx];
      } else {
        l -= 1048576;
        if (l < 131072) {                  // codebook [k][d]
          v = codebook[l];
        } else {
          l -= 131072;
          if (l < 16384){                  // ec1 B: [co][64] (k = ci*16+ky*4+kx, pad 48..63)
            int co = l>>6, k = l&63;
            v = (k < 48) ? ec1_w[co*48 + k] : 0.f;
          } else {                         // convT2 B: [n=co*16+t (pad to 64)][ci]
            l -= 16384;
            int n = l>>8, ci = l&255;
            v = (n < 48) ? dct2_w[ci*48 + n] : 0.f;
          }
        }
      }
    }
  }
  wp[idx] = f2bf(v);
}

// ---------------- im2col for conv1: x fp32 NCHW -> Xi [65536][64] bf16 ----------------
__global__ __launch_bounds__(256) void k_im2col(const float* __restrict__ x, bf16_t* __restrict__ Xi){
  int m = blockIdx.x*256 + threadIdx.x;
  int nn = m >> 12, oy = (m >> 6) & 63, ox = m & 63;
  bf16_t row[64];
#pragma unroll
  for (int k = 48; k < 64; k++) row[k] = f2bf(0.f);
#pragma unroll
  for (int ci = 0; ci < 3; ci++)
#pragma unroll
    for (int ky = 0; ky < 4; ky++){
      int iy = 2*oy + ky - 1;
      bool yok = (unsigned)iy < 128u;
#pragma unroll
      for (int kx = 0; kx < 4; kx++){
        int ix = 2*ox + kx - 1;
        float v = (yok && (unsigned)ix < 128u) ? x[((size_t)((nn*3+ci)*128 + iy))*128 + ix] : 0.f;
        row[ci*16 + ky*4 + kx] = f2bf(v);
      }
    }
#pragma unroll
  for (int u = 0; u < 8; u++){
    bf16x8 o;
#pragma unroll
    for (int e = 0; e < 8; e++) o[e] = row[u*8+e];
    *(bf16x8*)(Xi + (size_t)m*64 + u*8) = o;
  }
}

// ---------------- BN apply + ReLU, vectorized (interior only) ----------------
__global__ __launch_bounds__(256) void k_bnapply(const bf16_t* __restrict__ in, bf16_t* __restrict__ out,
    const float* __restrict__ stat, const float* __restrict__ g, const float* __restrict__ b,
    int hwlog, float invc)
{
  int idx = blockIdx.x*256 + threadIdx.x;
  int g8 = idx & 31, p = idx >> 5;
  int HW = 1 << hwlog, IW = HW + 2;
  int xx = p & (HW-1), yy = (p >> hwlog) & (HW-1), nn = p >> (2*hwlog);
  size_t a = ((size_t)((nn*IW + yy+1)*IW + xx+1))*256 + g8*8;
  float sm[8], sq[8], gv[8], bv[8];
#pragma unroll
  for (int e = 0; e < 8; e += 4){
    *(float4*)(sm+e) = *(const float4*)(stat + g8*8 + e);
    *(float4*)(sq+e) = *(const float4*)(stat + 256 + g8*8 + e);
    *(float4*)(gv+e) = *(const float4*)(g + g8*8 + e);
    *(float4*)(bv+e) = *(const float4*)(b + g8*8 + e);
  }
  bf16x8 v = *(const bf16x8*)(in + a);
  bf16x8 o;
#pragma unroll
  for (int e = 0; e < 8; e++){
    float mean = sm[e]*invc;
    float var  = sq[e]*invc - mean*mean;
    float sc = gv[e] * rsqrtf(var + 1e-5f);
    float sh = bv[e] - mean*sc;
    o[e] = f2bf(fmaxf(bf2f(v[e])*sc + sh, 0.f));
  }
  *(bf16x8*)(out + a) = o;
}

// ---------------- implicit-GEMM conv (MFMA bf16), TM=128, TN=64, BK=64 (XOR-swizzled LDS) ---------
// MODE: 0=k4s2 enc (66-halo), 1=k3s1 (34), 2=k1 (34), 3=convT k4s2 par (34->66),
//       5=im2col flat K=64, 6=k1 on 66-halo (convT2 tap-GEMM, N=64)
template<int MODE>
__global__ __launch_bounds__(256) void k_gemm(
    const bf16_t* __restrict__ in, const bf16_t* __restrict__ wp,
    const float* __restrict__ bias, const bf16_t* __restrict__ res,
    bf16_t* __restrict__ outb, float* __restrict__ outf,
    float* __restrict__ stat, int out_mode, float alpha)
{
  constexpr int TAPS = (MODE==0)?16:(MODE==1)?9:(MODE==3)?4:1;
  constexpr int CHUNKS = (MODE==5)?1:TAPS*4;
  const int N = gridDim.y * 64;

  __shared__ __align__(16) bf16_t As[128*64];
  __shared__ __align__(16) bf16_t Bs[64*64];
  __shared__ float s_sum[64], s_sum2[64];

  const int tid  = threadIdx.x;
  const int lane = tid & 63;
  const int wave = tid >> 6;
  const int m0   = blockIdx.x * 128;
  const int n0   = blockIdx.y * 64;
  int py = 0, px = 0;
  const bf16_t* wpp = wp;
  if (MODE == 3){ py = blockIdx.z >> 1; px = blockIdx.z & 1; wpp += (size_t)blockIdx.z * 262144; }

  // A staging slots: s = j*256 + wave*64 + lane ; row = s>>3 ; LDS unit s&7 holds
  // global unit (s&7)^(row&7)  (XOR swizzle -> conflict-free ds_read_b128 later)
  int abase[4];
#pragma unroll
  for (int j = 0; j < 4; j++){
    int s = j*256 + wave*64 + lane;
    int row = s >> 3, ug = (s & 7) ^ (row & 7);
    int m = m0 + row;
    int pbase;
    if (MODE == 0){ int nn=m>>10, sp=m&1023, oy=sp>>5, ox=sp&31; pbase = (nn*66 + 2*oy)*66 + 2*ox; }
    else if (MODE == 3){ int nn=m>>10, sp=m&1023, oy=sp>>5, ox=sp&31; pbase = (nn*34 + oy+1+py)*34 + ox+1+px; }
    else if (MODE == 5){ pbase = 0; }
    else if (MODE == 6){ int nn=m>>12, oy=(m>>6)&63, ox=m&63; pbase = (nn*66 + oy+1)*66 + ox+1; }
    else { int nn=m>>10, sp=m&1023, oy=sp>>5, ox=sp&31; pbase = (nn*34 + oy)*34 + ox; }
    abase[j] = (MODE==5) ? (m*64 + ug*8) : (pbase*256 + ug*8);
  }
  int bbase[2];
#pragma unroll
  for (int j = 0; j < 2; j++){
    int s = j*256 + wave*64 + lane;
    int row = s >> 3, ug = (s & 7) ^ (row & 7);
    bbase[j] = (MODE==5) ? ((n0+row)*64 + ug*8) : ((n0+row)*256 + ug*8);
  }

  f32x4 acc[4][2];
#pragma unroll
  for (int i = 0; i < 4; i++)
#pragma unroll
    for (int j = 0; j < 2; j++) acc[i][j] = (f32x4){0.f,0.f,0.f,0.f};

  const int rowbase = (wave >> 1) * 64;
  const int colbase = (wave & 1) * 32;
  const int mf = lane & 15;
  const int kq = lane >> 4;

  for (int c = 0; c < CHUNKS; ++c){
    int t = (MODE==5) ? 0 : (c >> 2);
    int koff;
    if (MODE == 0)      koff = ((t >> 2)*66 + (t & 3))*256 + ((c&3)<<6);
    else if (MODE == 1){ int ky = t/3; koff = (ky*34 + (t - ky*3))*256 + ((c&3)<<6); }
    else if (MODE == 2) koff = 35*256 + ((c&3)<<6);
    else if (MODE == 3) koff = -((t >> 1)*34 + (t & 1))*256 + ((c&3)<<6);
    else if (MODE == 6) koff = ((c&3)<<6);
    else                koff = 0;
    size_t bko = (MODE==5) ? 0 : ((size_t)t*N*256 + ((c&3)<<6));
#pragma unroll
    for (int j = 0; j < 4; j++)
      g2l16(in + abase[j] + koff, As + (j*256 + wave*64)*8);
#pragma unroll
    for (int j = 0; j < 2; j++)
      g2l16(wpp + bko + bbase[j], Bs + (j*256 + wave*64)*8);
    __syncthreads();

#pragma unroll
    for (int kk = 0; kk < 2; kk++){
      bf16x8 af[4], bfr[2];
#pragma unroll
      for (int i = 0; i < 4; i++){
        int rr = rowbase + i*16 + mf;
        af[i] = *reinterpret_cast<const bf16x8*>(&As[rr*64 + (((kk*4+kq) ^ (rr&7))<<3)]);
      }
#pragma unroll
      for (int j = 0; j < 2; j++){
        int rr = colbase + j*16 + mf;
        bfr[j] = *reinterpret_cast<const bf16x8*>(&Bs[rr*64 + (((kk*4+kq) ^ (rr&7))<<3)]);
      }
#pragma unroll
      for (int i = 0; i < 4; i++)
#pragma unroll
        for (int j = 0; j < 2; j++)
          acc[i][j] = __builtin_amdgcn_mfma_f32_16x16x32_bf16(af[i], bfr[j], acc[i][j], 0, 0, 0);
    }
    __syncthreads();
  }

  // epilogue: D[row=(lane>>4)*4+r][col=lane&15] ; fused per-channel sum/sumsq stats
  float psum[2] = {0.f, 0.f}, psum2[2] = {0.f, 0.f};
  const int rowq = (lane >> 4) * 4;
#pragma unroll
  for (int i = 0; i < 4; i++){
#pragma unroll
    for (int r = 0; r < 4; r++){
      int m = m0 + rowbase + i*16 + rowq + r;
      int nn, oy, ox;
      if (MODE == 5){ nn = m >> 12; oy = (m >> 6) & 63; ox = m & 63; }
      else { nn = m >> 10; oy = (m >> 5) & 31; ox = m & 31; }
#pragma unroll
      for (int j = 0; j < 2; j++){
        int co = n0 + colbase + j*16 + mf;
        float v = alpha * acc[i][j][r] + (bias ? bias[co] : 0.f);
        if (res) v += bf2f(res[((size_t)((nn*34 + oy+1)*34 + ox+1))*256 + co]);
        psum[j] += v; psum2[j] += v*v;
        if (out_mode == 2){
          outf[(size_t)m * N + co] = v;
        } else if (MODE == 3){
          outb[((size_t)((nn*66 + 2*oy+py+1)*66 + 2*ox+px+1))*256 + co] = f2bf(v);
        } else if (MODE == 5){
          outb[((size_t)((nn*66 + oy+1)*66 + ox+1))*256 + co] = f2bf(v);
        } else {
          outb[((size_t)((nn*34 + oy+1)*34 + ox+1))*256 + co] = f2bf(v);
          if (out_mode == 1)
            outf[(size_t)nn*262144 + (size_t)co*1024 + oy*32 + ox] = v;
        }
      }
    }
  }
  if (stat){
    if (tid < 64){ s_sum[tid] = 0.f; s_sum2[tid] = 0.f; }
    __syncthreads();
#pragma unroll
    for (int j = 0; j < 2; j++){
      int cl = colbase + j*16 + mf;
      atomicAdd(&s_sum[cl], psum[j]);
      atomicAdd(&s_sum2[cl], psum2[j]);
    }
    __syncthreads();
    if (tid < 64){
      atomicAdd(&stat[n0 + tid], s_sum[tid]);
      atomicAdd(&stat[256 + n0 + tid], s_sum2[tid]);
    }
  }
}

// ---------------- VQ argmin + gather -> z_q NCHW fp32 ----------------
__global__ __launch_bounds__(256) void k_vq_argmin(const float* __restrict__ scores,
    const float* __restrict__ cb, float* __restrict__ zq)
{
  __shared__ int best[32];
  __shared__ float Z[32*256];
  int tid = threadIdx.x, lane = tid & 63, wave = tid >> 6;
  int m0 = blockIdx.x * 32;
  int nn = m0 >> 10, y = (m0 >> 5) & 31;
  for (int rr = wave; rr < 32; rr += 4){
    const float* srow = scores + (size_t)(m0 + rr) * 512;
    float bv = 3.4e38f; int bk = 0;
    for (int k = lane; k < 512; k += 64){
      float v = srow[k];
      if (v < bv){ bv = v; bk = k; }
    }
    for (int off = 32; off; off >>= 1){
      float ov = __shfl_down(bv, off);
      int   ok = __shfl_down(bk, off);
      if (ov < bv || (ov == bv && ok < bk)){ bv = ov; bk = ok; }
    }
    if (lane == 0) best[rr] = bk;
  }
  __syncthreads();
  for (int rr = 0; rr < 32; rr++)
    Z[rr*256 + tid] = cb[best[rr]*256 + tid];
  __syncthreads();
  float* orow = zq + (size_t)nn*262144 + (size_t)tid*1024 + y*32;
#pragma unroll
  for (int x4 = 0; x4 < 8; x4++){
    float4 v;
    v.x = Z[(x4*4+0)*256 + tid];
    v.y = Z[(x4*4+1)*256 + tid];
    v.z = Z[(x4*4+2)*256 + tid];
    v.w = Z[(x4*4+3)*256 + tid];
    *(float4*)(orow + x4*4) = v;
  }
}

// ---------------- convT2 output assembly: x_rec[nn][co][oy2][ox2] from P + bias ----------------
// P[m][n] : m = input pixel (nn*4096 + iy*64 + ix), n = co*16 + ky*4 + kx (48 used, 64 pad)
__global__ __launch_bounds__(256) void k_ct2asm(const float* __restrict__ P,
    const float* __restrict__ bias, float* __restrict__ out)
{
  int idx = blockIdx.x*256 + threadIdx.x;   // 262144 = 16*128*128
  int nn = idx >> 14, oy2 = (idx >> 7) & 127, ox2 = idx & 127;
  int py = oy2 & 1, px = ox2 & 1, oyh = oy2 >> 1, oxh = ox2 >> 1;
  float a0 = bias[0], a1 = bias[1], a2 = bias[2];
#pragma unroll
  for (int a = 0; a < 2; a++){
    int iy = oyh + py - a;
    if ((unsigned)iy > 63u) continue;
    int ky = 2*a + 1 - py;
#pragma unroll
    for (int b = 0; b < 2; b++){
      int ix = oxh + px - b;
      if ((unsigned)ix > 63u) continue;
      int kx = 2*b + 1 - px;
      const float* pr = P + ((size_t)(nn*4096 + iy*64 + ix))*64 + ky*4 + kx;
      a0 += pr[0]; a1 += pr[16]; a2 += pr[32];
    }
  }
  size_t o = (size_t)nn*49152 + (size_t)oy2*128 + ox2;
  out[o]         = a0;
  out[o + 16384] = a1;
  out[o + 32768] = a2;
}

// ---------------- host ----------------
extern "C" void kernel_launch(void* const* d_in, const int* in_sizes, int n_in,
                              void* d_out, int out_size, void* d_ws, size_t ws_size,
                              hipStream_t stream)
{
  if (ws_size < (size_t)WS_NEEDED) return;

  const float* x       = (const float*)d_in[0];
  const float* ec1_w   = (const float*)d_in[1];
  const float* ec1_b   = (const float*)d_in[2];
  const float* ebn1_g  = (const float*)d_in[3];
  const float* ebn1_b  = (const float*)d_in[4];
  const float* ec2_w   = (const float*)d_in[5];
  const float* ec2_b   = (const float*)d_in[6];
  const float* rb_bn1_g= (const float*)d_in[7];
  const float* rb_bn1_b= (const float*)d_in[8];
  const float* rb_c3_w = (const float*)d_in[9];
  const float* rb_c3_b = (const float*)d_in[10];
  const float* rb_bn2_g= (const float*)d_in[11];
  const float* rb_bn2_b= (const float*)d_in[12];
  const float* rb_c1_w = (const float*)d_in[13];
  const float* rb_c1_b = (const float*)d_in[14];
  const float* dbn1_g  = (const float*)d_in[15];
  const float* dbn1_b  = (const float*)d_in[16];
  const float* dct1_w  = (const float*)d_in[17];
  const float* dct1_b  = (const float*)d_in[18];
  const float* dbn2_g  = (const float*)d_in[19];
  const float* dbn2_b  = (const float*)d_in[20];
  const float* dct2_w  = (const float*)d_in[21];
  const float* dct2_b  = (const float*)d_in[22];
  const float* codebook= (const float*)d_in[23];

  char* ws = (char*)d_ws;
  bf16_t* A64 = (bf16_t*)ws;
  float*  scores = (float*)ws;                    // overlaps A64 (A64 halo unused afterwards)
  bf16_t* SB0 = (bf16_t*)(ws + SB0_OFF);
  bf16_t* SB1 = (bf16_t*)(ws + SB0_OFF + 1*SB_BYTES);
  bf16_t* SB2 = (bf16_t*)(ws + SB0_OFF + 2*SB_BYTES);
  bf16_t* SB3 = (bf16_t*)(ws + SB0_OFF + 3*SB_BYTES);
  float*  P   = (float*)(ws + SB0_OFF + 1*SB_BYTES);   // overlaps SB1+SB2 (dead at convT2 time)
  float*  stats = (float*)(ws + STATS_OFF);
  float*  cbn   = (float*)(ws + CBN_OFF);
  bf16_t* Wp    = (bf16_t*)(ws + WP_OFF);
  bf16_t* Xi    = (bf16_t*)(ws + XI_OFF);

  float* xrec = (float*)d_out;
  float* zef  = xrec + 786432;
  float* zqf  = zef + 4194304;

  // prep (one kernel: all halos + stats) ; repack+cbnorm (one kernel)
  k_prep  <<<dim3(1583),  256, 0, stream>>>(A64, SB0, (uint4*)(ws + STATS_OFF));
  k_repack<<<dim3(19074), 256, 0, stream>>>(ec2_w, rb_c3_w, rb_c1_w, dct1_w, codebook,
                                            ec1_w, dct2_w, Wp, cbn);

  // encoder conv1 (im2col + GEMM, stats slot0 fused) + ebn1 apply
  k_im2col<<<dim3(256), 256, 0, stream>>>(x, Xi);
  k_gemm<5><<<dim3(512,4,1), 256, 0, stream>>>(Xi, Wp + WP_EC1, ec1_b, nullptr, A64, nullptr,
                                               stats, 0, 1.f);
  k_bnapply<<<dim3(8192), 256, 0, stream>>>(A64, A64, stats, ebn1_g, ebn1_b, 6, 1.f/65536.f);
  // encoder conv2 (k4 s2): A64 -> SB0, stats slot1 (rb0.bn1)
  k_gemm<0><<<dim3(128,4,1), 256, 0, stream>>>(A64, Wp, ec2_b, nullptr, SB0, nullptr,
                                               stats + 1*512, 0, 1.f);

  auto launch_rb = [&](bf16_t* xin, bf16_t* xout, int i, int sIn, int sMid, int sOut, float* zf){
    k_bnapply<<<dim3(2048), 256, 0, stream>>>(xin, SB1, stats + sIn*512,
                                              rb_bn1_g + i*256, rb_bn1_b + i*256, 5, 1.f/16384.f);
    k_gemm<1><<<dim3(128,4,1), 256, 0, stream>>>(SB1, Wp + WP_RB3(i), rb_c3_b + i*256,
                                                 nullptr, SB2, nullptr, stats + sMid*512, 0, 1.f);
    k_bnapply<<<dim3(2048), 256, 0, stream>>>(SB2, SB2, stats + sMid*512,
                                              rb_bn2_g + i*256, rb_bn2_b + i*256, 5, 1.f/16384.f);
    k_gemm<2><<<dim3(128,4,1), 256, 0, stream>>>(SB2, Wp + WP_RB1(i), rb_c1_b + i*256,
                                                 xin, xout, zf, stats + sOut*512, zf ? 1 : 0, 1.f);
  };

  // resblocks 0,1 -> z_e
  launch_rb(SB0, SB3, 0, 1, 2, 3, nullptr);
  launch_rb(SB3, SB0, 1, 3, 4, 5, zef);

  // VQ: scores = |c|^2 - 2 z.c ; argmin + gather (scores overlaps A64)
  k_gemm<2><<<dim3(128,8,1), 256, 0, stream>>>(SB0, Wp + WP_CB, cbn, nullptr, nullptr, scores,
                                               nullptr, 2, -2.f);
  k_vq_argmin<<<dim3(512), 256, 0, stream>>>(scores, codebook, zqf);

  // decoder resblocks 2,3
  launch_rb(SB0, SB3, 2, 5, 6, 7, nullptr);
  launch_rb(SB3, SB0, 3, 7, 8, 9, nullptr);

  // dbn1 apply + convT1 (parity GEMM, fused dbn2 stats) -> A64 (interior fully rewritten)
  k_bnapply<<<dim3(2048), 256, 0, stream>>>(SB0, SB0, stats + 9*512, dbn1_g, dbn1_b, 5, 1.f/16384.f);
  k_gemm<3><<<dim3(128,4,4), 256, 0, stream>>>(SB0, Wp + WP_CT, dct1_b, nullptr, A64, nullptr,
                                               stats + 10*512, 0, 1.f);

  // dbn2 apply + convT2 tap-GEMM (M=65536, N=64, K=256) -> P, then assembly -> x_rec
  k_bnapply<<<dim3(8192), 256, 0, stream>>>(A64, A64, stats + 10*512, dbn2_g, dbn2_b, 6, 1.f/65536.f);
  k_gemm<6><<<dim3(512,1,1), 256, 0, stream>>>(A64, Wp + WP_CT2, nullptr, nullptr, nullptr, P,
                                               nullptr, 2, 1.f);
  k_ct2asm<<<dim3(1024), 256, 0, stream>>>(P, dct2_b, xrec);
}